// Round 4
// baseline (203.085 us; speedup 1.0000x reference)
//
#include <hip/hip_runtime.h>

// CapsNet dynamic routing — 8 streaming launches, small blocks, 4 blocks/CU.
//   prep_w: W fp32 -> Wy (s-GEMM frag order), WTd (u-GEMM frag order)
//   kX:  x fp32 -> x16y + xTd (both frag layouts), pure streaming, no LDS.
//   kR:  grid 1024 = (batch b, i-quarter q), block 256 (4 waves).
//        mode 0: softmax(b_init) -> partial y/csum
//        mode 1: delta = u0 @ xT (frags direct from global xTd), b = b_init
//                + D0 + vb0, checkpoint b2 (fp32), softmax, partial y
//        mode 2: b = b2 + D1 + vb1, softmax, partial y
//   k2:  grid 256 = (j, 32-batch chunk), block 512. Stages 4 y-quarters,
//        chains 4 MFMAs/kt. squash, then u-GEMM -> u16 (+vb) or vout.

#define BSZ 256

typedef _Float16 f16x8 __attribute__((ext_vector_type(8)));
typedef float f32x4 __attribute__((ext_vector_type(4)));

// ---------------------------------------------------------------------------
// prep_w: grid 32 (block=j), block 256.
// Wy  f16x8 idx (per j, 2048 vecs): kt*256 + d*4 + quad   (kt=c>>5, e=c&7)
// WTd f16x8 idx (per j, 2048 vecs): kt*1024 + cc*4 + quad (kt=d>>5, e=d&7)
// ---------------------------------------------------------------------------
__global__ __launch_bounds__(256) void prep_w(
    const float* __restrict__ W,     // [32*64][256]
    _Float16* __restrict__ Wy,
    _Float16* __restrict__ WTd)
{
  __shared__ __align__(16) float Wsh[64 * 260];
  const int j = blockIdx.x, t = threadIdx.x;

  #pragma unroll
  for (int k = 0; k < 16; ++k) {
    const int q = k * 256 + t;
    const int row = q >> 6, c4 = (q & 63) * 4;
    *reinterpret_cast<f32x4*>(&Wsh[row * 260 + c4]) =
        *reinterpret_cast<const f32x4*>(&W[((size_t)j * 64 + row) * 256 + c4]);
  }
  __syncthreads();

  {
    const int d = t & 63, quad = t >> 6;
    f16x8* out = reinterpret_cast<f16x8*>(Wy) + (size_t)j * 2048;
    #pragma unroll
    for (int kt = 0; kt < 8; ++kt) {
      const int c0 = kt * 32 + quad * 8;
      f16x8 hv;
      #pragma unroll
      for (int e = 0; e < 8; ++e) hv[e] = (_Float16)Wsh[d * 260 + c0 + e];
      out[kt * 256 + d * 4 + quad] = hv;
    }
  }
  {
    const int cc = t;
    f16x8* out = reinterpret_cast<f16x8*>(WTd) + (size_t)j * 2048;
    #pragma unroll
    for (int h8 = 0; h8 < 8; ++h8) {
      const int kt = h8 >> 2, quad = h8 & 3;
      f16x8 hv;
      #pragma unroll
      for (int e = 0; e < 8; ++e)
        hv[e] = (_Float16)Wsh[(h8 * 8 + e) * 260 + cc];
      out[kt * 1024 + cc * 4 + quad] = hv;
    }
  }
}

// ---------------------------------------------------------------------------
// kX: grid 512 (b = bid>>1, h = bid&1), block 256. No LDS.
// x16y f16x8 idx (per b, 8192): kk*1024 + c*4 + quad (kk=i>>5, quad=(i>>3)&3,
//   e=i&7)
// xTd  f16x8 idx (per b, 8192): kt*1024 + i*4 + qd  (kt=c>>5, qd=(c>>3)&3,
//   e=c&7)
// ---------------------------------------------------------------------------
__global__ __launch_bounds__(256, 4) void kX(
    const float* __restrict__ x,        // [b][c][i] fp32
    _Float16* __restrict__ x16y,
    _Float16* __restrict__ xTd)
{
  const int bid = blockIdx.x, t = threadIdx.x;
  const int b = bid >> 1, h = bid & 1;
  const float* xb = x + (size_t)b * 65536;

  // ---- pass A: rows -> x16y ----
  f16x8* xy8 = reinterpret_cast<f16x8*>(x16y) + (size_t)b * 8192;
  #pragma unroll
  for (int pp = 0; pp < 4; ++pp) {
    const int p = pp * 256 + t;          // 1024 (c4, i8) tiles in this half
    const int i8l = (p & 15) * 8;        // 0..120
    const int c4 = (p >> 4) * 4;         // 0..252
    const int ig8 = h * 128 + i8l;
    const int kk = ig8 >> 5, qd = (ig8 >> 3) & 3;
    f32x4 v[4][2];
    #pragma unroll
    for (int s = 0; s < 4; ++s) {
      v[s][0] = *reinterpret_cast<const f32x4*>(&xb[(c4 + s) * 256 + ig8]);
      v[s][1] = *reinterpret_cast<const f32x4*>(&xb[(c4 + s) * 256 + ig8 + 4]);
    }
    #pragma unroll
    for (int s = 0; s < 4; ++s) {
      f16x8 hv;
      #pragma unroll
      for (int e = 0; e < 4; ++e) {
        hv[e] = (_Float16)v[s][0][e];
        hv[4 + e] = (_Float16)v[s][1][e];
      }
      xy8[kk * 1024 + (c4 + s) * 4 + qd] = hv;
    }
  }

  // ---- pass B: columns (L2-hot re-read) -> xTd, coalesced writes ----
  f16x8* xt8 = reinterpret_cast<f16x8*>(xTd) + (size_t)b * 8192;
  #pragma unroll
  for (int r = 0; r < 16; ++r) {
    const int lv = r * 256 + t;          // 4096 xTd vecs in this half
    const int kt = lv >> 9, s = lv & 511;
    const int il = s >> 2, qd = s & 3;
    const int ig = h * 128 + il;
    const int c0 = kt * 32 + qd * 8;
    f16x8 hv;
    #pragma unroll
    for (int e = 0; e < 8; ++e)
      hv[e] = (_Float16)xb[(c0 + e) * 256 + ig];
    xt8[kt * 1024 + h * 512 + s] = hv;   // == kt*1024 + ig*4 + qd
  }
}

// ---------------------------------------------------------------------------
// kR: grid 1024 (b = bid>>2, q = bid&3), block 256 (4 waves, 4 blocks/CU).
// Wave wv owns i columns ig = q*64 + wv*16 + l15.
// delta B-frag: xTd vec[kt*1024 + ig*4 + quad]      (global, 1KB/wave)
// y     B-frag: x16y vec[(q*2+kk)*1024 + c*4 + quad] (global, 1KB/wave)
// ---------------------------------------------------------------------------
__global__ __launch_bounds__(256, 4) void kR(
    const _Float16* __restrict__ x16y,
    const _Float16* __restrict__ xTd,
    const _Float16* __restrict__ u,     // [b][j][c]  (modes 1,2)
    const float* __restrict__ vb,       // [b][j]     (modes 1,2)
    const float* __restrict__ bsrc,     // [b][j][i]  (b_init or b2)
    float* __restrict__ b2out,          // [b][j][i]  (mode 1 writes)
    _Float16* __restrict__ yqs,         // [4 q][b][j][c] partials
    float* __restrict__ csumQ,          // [4 q][b][j] partials
    int mode)
{
  __shared__ __align__(16) _Float16 SB[32 * 264];  // u stage -> y repack
  __shared__ __align__(16) _Float16 cs[32 * 72];   // softmax out (this q)
  __shared__ float vbs[32];
  __shared__ float csumsh[32];

  const int bid = blockIdx.x, t = threadIdx.x;
  const int b = bid >> 2, q = bid & 3;
  const int wv = t >> 6, lane = t & 63, l15 = lane & 15, quad = lane >> 4;
  const int ig = q * 64 + wv * 16 + l15;   // global i column
  const float* bp = bsrc + (size_t)b * 8192;

  if (mode != 0) {
    const f16x8* ug = reinterpret_cast<const f16x8*>(u + (size_t)b * 8192);
    #pragma unroll
    for (int pp = 0; pp < 4; ++pp) {
      const int p = pp * 256 + t;
      *reinterpret_cast<f16x8*>(&SB[(p >> 5) * 264 + (p & 31) * 8]) = ug[p];
    }
    if (t < 32) vbs[t] = vb[b * 32 + t];
  }
  if (t < 32) csumsh[t] = 0.f;

  // routing logits (coalesced, overlap staging)
  float breg[2][4];
  #pragma unroll
  for (int mt = 0; mt < 2; ++mt)
    #pragma unroll
    for (int rr = 0; rr < 4; ++rr)
      breg[mt][rr] = bp[(mt * 16 + quad * 4 + rr) * 256 + ig];

  __syncthreads();  // B1: SB/vbs staged, csumsh zeroed

  if (mode != 0) {
    // ---- delta-GEMM: D[j, ig] = sum_c u[j,c] x[c,ig] ----
    const f16x8* xt8 = reinterpret_cast<const f16x8*>(xTd) + (size_t)b * 8192;
    f32x4 acc0 = (f32x4){0.f, 0.f, 0.f, 0.f};
    f32x4 acc1 = (f32x4){0.f, 0.f, 0.f, 0.f};
    #pragma unroll
    for (int kt = 0; kt < 8; ++kt) {
      const int ko = kt * 32 + quad * 8;
      f16x8 bf = xt8[kt * 1024 + ig * 4 + quad];   // coalesced global
      f16x8 a0 = *reinterpret_cast<const f16x8*>(&SB[l15 * 264 + ko]);
      f16x8 a1 = *reinterpret_cast<const f16x8*>(&SB[(16 + l15) * 264 + ko]);
      acc0 = __builtin_amdgcn_mfma_f32_16x16x32_f16(a0, bf, acc0, 0, 0, 0);
      acc1 = __builtin_amdgcn_mfma_f32_16x16x32_f16(a1, bf, acc1, 0, 0, 0);
    }
    #pragma unroll
    for (int rr = 0; rr < 4; ++rr) {
      const int j0 = quad * 4 + rr;
      breg[0][rr] += acc0[rr] + vbs[j0];
      breg[1][rr] += acc1[rr] + vbs[16 + j0];
    }
    if (mode == 1) {
      // checkpoint b2 = b_init + D0 + vb0 (fp32, bit-identical to recompute)
      float* bo = b2out + (size_t)b * 8192;
      #pragma unroll
      for (int mt = 0; mt < 2; ++mt)
        #pragma unroll
        for (int rr = 0; rr < 4; ++rr)
          bo[(mt * 16 + quad * 4 + rr) * 256 + ig] = breg[mt][rr];
    }
  }

  // ---- softmax over j (registers + shfl across quads/halves) ----
  float cf[2][4];
  {
    float m = breg[0][0];
    #pragma unroll
    for (int mt = 0; mt < 2; ++mt)
      #pragma unroll
      for (int rr = 0; rr < 4; ++rr) m = fmaxf(m, breg[mt][rr]);
    m = fmaxf(m, __shfl_xor(m, 16));
    m = fmaxf(m, __shfl_xor(m, 32));
    float s = 0.f;
    #pragma unroll
    for (int mt = 0; mt < 2; ++mt)
      #pragma unroll
      for (int rr = 0; rr < 4; ++rr) {
        float e = __expf(breg[mt][rr] - m);
        cf[mt][rr] = e; s += e;
      }
    s += __shfl_xor(s, 16);
    s += __shfl_xor(s, 32);
    const float rinv = 1.f / s;
    const int il = wv * 16 + l15;   // local column 0..63
    #pragma unroll
    for (int mt = 0; mt < 2; ++mt)
      #pragma unroll
      for (int rr = 0; rr < 4; ++rr) {
        const float cv = cf[mt][rr] * rinv;
        cf[mt][rr] = cv;
        cs[(mt * 16 + quad * 4 + rr) * 72 + il] = (_Float16)cv;
      }
  }
  __syncthreads();  // B2: cs visible; all SB u-reads complete

  // csum[j] quarter-partial
  #pragma unroll
  for (int mt = 0; mt < 2; ++mt)
    #pragma unroll
    for (int rr = 0; rr < 4; ++rr) {
      float pj = cf[mt][rr];
      pj += __shfl_xor(pj, 1);
      pj += __shfl_xor(pj, 2);
      pj += __shfl_xor(pj, 4);
      pj += __shfl_xor(pj, 8);
      if (l15 == 0) atomicAdd(&csumsh[mt * 16 + quad * 4 + rr], pj);
    }

  // ---- partial y[j,c] = sum_{i in quarter} c[j,i] x[c,i] ----
  // wave wv covers c strip wv*64..wv*64+63 (4 n-tiles), kk 0..1 local i.
  const f16x8* xy8 = reinterpret_cast<const f16x8*>(x16y) + (size_t)b * 8192;
  f32x4 acy[2][4];
  #pragma unroll
  for (int mt = 0; mt < 2; ++mt)
    #pragma unroll
    for (int nt = 0; nt < 4; ++nt)
      acy[mt][nt] = (f32x4){0.f, 0.f, 0.f, 0.f};
  #pragma unroll
  for (int kk = 0; kk < 2; ++kk) {
    const int kkg = q * 2 + kk;
    const int ko = kk * 32 + quad * 8;
    f16x8 a0 = *reinterpret_cast<const f16x8*>(&cs[l15 * 72 + ko]);
    f16x8 a1 = *reinterpret_cast<const f16x8*>(&cs[(16 + l15) * 72 + ko]);
    #pragma unroll
    for (int nt = 0; nt < 4; ++nt) {
      const int c = wv * 64 + nt * 16 + l15;
      f16x8 bf = xy8[kkg * 1024 + c * 4 + quad];   // coalesced global
      acy[0][nt] = __builtin_amdgcn_mfma_f32_16x16x32_f16(a0, bf, acy[0][nt], 0, 0, 0);
      acy[1][nt] = __builtin_amdgcn_mfma_f32_16x16x32_f16(a1, bf, acy[1][nt], 0, 0, 0);
    }
  }

  // repack D-layout -> SB (u-reads finished at B2)
  #pragma unroll
  for (int mt = 0; mt < 2; ++mt)
    #pragma unroll
    for (int nt = 0; nt < 4; ++nt)
      #pragma unroll
      for (int rr = 0; rr < 4; ++rr)
        SB[(mt * 16 + quad * 4 + rr) * 264 + wv * 64 + nt * 16 + l15] =
            (_Float16)acy[mt][nt][rr];
  __syncthreads();  // B3: SB repack + csum atomics complete

  {
    _Float16* yo = yqs + ((size_t)(q * BSZ + b)) * 8192;
    #pragma unroll
    for (int pp = 0; pp < 4; ++pp) {
      const int p = pp * 256 + t;
      const int row = p >> 5, co = (p & 31) * 8;
      *reinterpret_cast<f16x8*>(&yo[row * 256 + co]) =
          *reinterpret_cast<const f16x8*>(&SB[row * 264 + co]);
    }
  }
  if (t < 32) csumQ[(q * BSZ + b) * 32 + t] = csumsh[t];
}

// ---------------------------------------------------------------------------
// k2: grid 256 = 32 j x 8 chunks of 32 batches, block 512 (8 waves).
// ---------------------------------------------------------------------------
__global__ __launch_bounds__(512) void k2(
    const _Float16* __restrict__ Wy,
    const _Float16* __restrict__ WTd,
    const float* __restrict__ bias,
    const _Float16* __restrict__ yqs,   // [4 q][b][j][c] partials
    const float* __restrict__ csumQ,    // [4 q][b][j] partials
    _Float16* __restrict__ u16,         // [b][j][c] (target buffer)
    float* __restrict__ vb_ws,          // [b][j]
    float* __restrict__ vout,           // [b][j][d]
    int final_iter)
{
  __shared__ __align__(16) _Float16 ysh[4][32 * 264];  // stages; [0] u-repack
  __shared__ __align__(16) _Float16 vsh[32 * 72];
  __shared__ float n2sh[32];
  __shared__ float vbsh[32];
  __shared__ float csums[32];

  const int jb = blockIdx.x & 31;
  const int b0 = (blockIdx.x >> 5) * 32;
  const int t = threadIdx.x;
  const int w = t >> 6, lane = t & 63, l15 = lane & 15, quad = lane >> 4;

  #pragma unroll
  for (int p0 = 0; p0 < 2; ++p0) {
    const int p = p0 * 512 + t;
    const int bs = p >> 5, co = (p & 31) * 8;
    #pragma unroll
    for (int qq = 0; qq < 4; ++qq)
      *reinterpret_cast<f16x8*>(&ysh[qq][bs * 264 + co]) =
          *reinterpret_cast<const f16x8*>(
              &yqs[((size_t)(qq * BSZ + b0 + bs)) * 8192 + jb * 256 + co]);
  }
  if (t < 32) {
    float cacc = 0.f;
    #pragma unroll
    for (int qq = 0; qq < 4; ++qq)
      cacc += csumQ[(qq * BSZ + b0 + t) * 32 + jb];
    csums[t] = cacc;
    n2sh[t] = 0.f;
    vbsh[t] = 0.f;
  }
  __syncthreads();

  // ---- s-GEMM: wave w -> (mt = w&1, nt = w>>1); W prefetched ----
  const int mt = w & 1, nt = w >> 1;
  const int d = nt * 16 + l15;
  f16x8 wreg[8];
  {
    const f16x8* Wg8 = reinterpret_cast<const f16x8*>(Wy) + (size_t)jb * 2048;
    #pragma unroll
    for (int kt = 0; kt < 8; ++kt) wreg[kt] = Wg8[kt * 256 + d * 4 + quad];
  }
  f32x4 sacc = (f32x4){0.f, 0.f, 0.f, 0.f};
  #pragma unroll
  for (int kt = 0; kt < 8; ++kt) {
    const int ko = kt * 32 + quad * 8;
    #pragma unroll
    for (int qq = 0; qq < 4; ++qq) {
      f16x8 a =
          *reinterpret_cast<const f16x8*>(&ysh[qq][(mt * 16 + l15) * 264 + ko]);
      sacc = __builtin_amdgcn_mfma_f32_16x16x32_f16(a, wreg[kt], sacc, 0, 0, 0);
    }
  }
  const float biasd = bias[jb * 64 + d];
  float sv[4];
  #pragma unroll
  for (int rr = 0; rr < 4; ++rr)
    sv[rr] = sacc[rr] + biasd * csums[mt * 16 + quad * 4 + rr];

  #pragma unroll
  for (int rr = 0; rr < 4; ++rr) {
    float p = sv[rr] * sv[rr];
    p += __shfl_xor(p, 1);
    p += __shfl_xor(p, 2);
    p += __shfl_xor(p, 4);
    p += __shfl_xor(p, 8);
    if (l15 == 0) atomicAdd(&n2sh[mt * 16 + quad * 4 + rr], p);
  }
  __syncthreads();

  float vv[4];
  #pragma unroll
  for (int rr = 0; rr < 4; ++rr) {
    const float n2 = n2sh[mt * 16 + quad * 4 + rr];
    const float sc = sqrtf(n2) / (1.f + n2);
    vv[rr] = sv[rr] * sc;
  }

  if (final_iter) {
    #pragma unroll
    for (int rr = 0; rr < 4; ++rr)
      vout[((size_t)(b0 + mt * 16 + quad * 4 + rr) * 32 + jb) * 64 + d] = vv[rr];
  } else {
    #pragma unroll
    for (int rr = 0; rr < 4; ++rr) {
      vsh[(mt * 16 + quad * 4 + rr) * 72 + d] = (_Float16)vv[rr];
      float p = vv[rr] * biasd;
      p += __shfl_xor(p, 1);
      p += __shfl_xor(p, 2);
      p += __shfl_xor(p, 4);
      p += __shfl_xor(p, 8);
      if (l15 == 0) atomicAdd(&vbsh[mt * 16 + quad * 4 + rr], p);
    }
    __syncthreads();   // vsh/vbsh complete; ysh reads done -> reuse ysh[0]
    if (t < 32) vb_ws[(b0 + t) * 32 + jb] = vbsh[t];

    // ---- u-GEMM: wave w -> (mt, ntu = (w>>1)*4 + qx) ----
    const f16x8* WT8 = reinterpret_cast<const f16x8*>(WTd) + (size_t)jb * 2048;
    #pragma unroll
    for (int qx = 0; qx < 4; ++qx) {
      const int ntu = (w >> 1) * 4 + qx;
      const int cc = ntu * 16 + l15;
      f32x4 ua = (f32x4){0.f, 0.f, 0.f, 0.f};
      #pragma unroll
      for (int kt = 0; kt < 2; ++kt) {
        const int ko = kt * 32 + quad * 8;
        f16x8 a =
            *reinterpret_cast<const f16x8*>(&vsh[(mt * 16 + l15) * 72 + ko]);
        f16x8 bf = WT8[kt * 1024 + cc * 4 + quad];   // coalesced (L2)
        ua = __builtin_amdgcn_mfma_f32_16x16x32_f16(a, bf, ua, 0, 0, 0);
      }
      #pragma unroll
      for (int rr = 0; rr < 4; ++rr)
        ysh[0][(mt * 16 + quad * 4 + rr) * 264 + cc] = (_Float16)ua[rr];
    }
    __syncthreads();
    // coalesced u16 write-out
    #pragma unroll
    for (int p0 = 0; p0 < 2; ++p0) {
      const int p = p0 * 512 + t;
      const int bs = p >> 5, co = (p & 31) * 8;
      *reinterpret_cast<f16x8*>(&u16[(size_t)(b0 + bs) * 8192 + jb * 256 + co]) =
          *reinterpret_cast<const f16x8*>(&ysh[0][bs * 264 + co]);
    }
  }
}

// ---------------------------------------------------------------------------
extern "C" void kernel_launch(void* const* d_in, const int* in_sizes, int n_in,
                              void* d_out, int out_size, void* d_ws, size_t ws_size,
                              hipStream_t stream) {
  (void)in_sizes; (void)n_in; (void)out_size; (void)ws_size;
  const float* x      = (const float*)d_in[0];
  const float* W      = (const float*)d_in[1];
  const float* bias   = (const float*)d_in[2];
  const float* b_init = (const float*)d_in[3];
  char* ws = (char*)d_ws;

  _Float16* x16y  = (_Float16*)(ws);                            // 32 MiB
  _Float16* xTd   = (_Float16*)(ws + (32u << 20));              // 32 MiB
  _Float16* yqs   = (_Float16*)(ws + (64u << 20));              // 16 MiB (4 q)
  _Float16* u16a  = (_Float16*)(ws + (80u << 20));              // 4 MiB
  _Float16* u16b  = (_Float16*)(ws + (84u << 20));              // 4 MiB
  float*    b2    = (float*)(ws + (88u << 20));                 // 8 MiB
  _Float16* Wy    = (_Float16*)(ws + (96u << 20));              // 1 MiB
  _Float16* WTd   = (_Float16*)(ws + (97u << 20));              // 1 MiB
  float*    csumQ = (float*)(ws + (98u << 20));                 // 128 KiB (4 q)
  float*    vb0   = (float*)(ws + (98u << 20) + (128u << 10));  // 32 KiB
  float*    vb1   = (float*)(ws + (98u << 20) + (160u << 10));  // 32 KiB
  float*    vout  = (float*)d_out;

  prep_w<<<32, 256, 0, stream>>>(W, Wy, WTd);
  kX<<<512, 256, 0, stream>>>(x, x16y, xTd);
  // iter 1: softmax(b_init), partial y
  kR<<<1024, 256, 0, stream>>>(x16y, xTd, u16a, vb0, b_init, b2, yqs, csumQ, 0);
  k2<<<256, 512, 0, stream>>>(Wy, WTd, bias, yqs, csumQ, u16a, vb0, vout, 0);
  // iter 2: b = b_init + D(u0)+vb0, checkpoint b2
  kR<<<1024, 256, 0, stream>>>(x16y, xTd, u16a, vb0, b_init, b2, yqs, csumQ, 1);
  k2<<<256, 512, 0, stream>>>(Wy, WTd, bias, yqs, csumQ, u16b, vb1, vout, 0);
  // iter 3: b = b2 + D(u1)+vb1 (single delta pass)
  kR<<<1024, 256, 0, stream>>>(x16y, xTd, u16b, vb1, b2, b2, yqs, csumQ, 2);
  k2<<<256, 512, 0, stream>>>(Wy, WTd, bias, yqs, csumQ, u16a, vb0, vout, 1);
}

// Round 5
// 193.551 us; speedup vs baseline: 1.0493x; 1.0493x over previous
//
#include <hip/hip_runtime.h>

// CapsNet dynamic routing — 7 launches, no-LDS-x routing kernel.
//   kXW: blocks 0-511: x fp32 -> x16y + xTd (both frag layouts, streaming,
//        pass B L2-hot column re-read, coalesced writes). Blocks 512-543:
//        W fp32 -> Wy + WTd (no LDS).
//   kR:  grid 256 (block=batch), block 1024 (16 waves). No x staging:
//        both GEMMs read B-frags direct from global frag buffers
//        (L3-resident, 1KB/wave coalesced, pipelined into MFMA loop).
//        LDS only for u (16KB) + cs (17KB). mode 0: softmax(b_init)+y.
//        mode 1: delta=u0@xT, b=b_init+D0+vb0, checkpoint b2 (fp32), y.
//        mode 2: b=b2+D1+vb1, y.
//   k2:  grid 256 = (j, 32-batch chunk), block 512. W frags prefetched to
//        regs. s-GEMM + bias*csum, squash, then u-GEMM -> u16 (+vb) or vout.

#define BSZ 256

typedef _Float16 f16x8 __attribute__((ext_vector_type(8)));
typedef float f32x4 __attribute__((ext_vector_type(4)));

// ---------------------------------------------------------------------------
// kXW: grid 544, block 256.
// x16y f16x8 idx (per b, 8192): kk*1024 + c*4 + quad (kk=i>>5, quad=(i>>3)&3,
//   e=i&7)
// xTd  f16x8 idx (per b, 8192): kt*1024 + i*4 + qd  (kt=c>>5, qd=(c>>3)&3,
//   e=c&7)
// Wy  f16x8 idx (per j, 2048): kt*256 + d*4 + quad   (kt=c>>5, e=c&7)
// WTd f16x8 idx (per j, 2048): kt*1024 + cc*4 + quad (kt=d>>5, e=d&7)
// ---------------------------------------------------------------------------
__global__ __launch_bounds__(256) void kXW(
    const float* __restrict__ x,        // [b][c][i] fp32
    const float* __restrict__ W,        // [32*64][256] fp32
    _Float16* __restrict__ x16y,
    _Float16* __restrict__ xTd,
    _Float16* __restrict__ Wy,
    _Float16* __restrict__ WTd)
{
  const int t = threadIdx.x;

  if (blockIdx.x >= 512) {
    // ---- W prep (no LDS): j = blockIdx.x - 512 ----
    const int j = blockIdx.x - 512;
    const float* Wj = W + (size_t)j * 64 * 256;
    {
      const int d = t & 63, quad = t >> 6;
      f16x8* out = reinterpret_cast<f16x8*>(Wy) + (size_t)j * 2048;
      #pragma unroll
      for (int kt = 0; kt < 8; ++kt) {
        const int c0 = kt * 32 + quad * 8;
        f32x4 v0 = *reinterpret_cast<const f32x4*>(&Wj[d * 256 + c0]);
        f32x4 v1 = *reinterpret_cast<const f32x4*>(&Wj[d * 256 + c0 + 4]);
        f16x8 hv;
        #pragma unroll
        for (int e = 0; e < 4; ++e) {
          hv[e] = (_Float16)v0[e];
          hv[4 + e] = (_Float16)v1[e];
        }
        out[kt * 256 + d * 4 + quad] = hv;
      }
    }
    {
      const int cc = t;
      f16x8* out = reinterpret_cast<f16x8*>(WTd) + (size_t)j * 2048;
      #pragma unroll
      for (int h8 = 0; h8 < 8; ++h8) {
        const int kt = h8 >> 2, quad = h8 & 3;
        f16x8 hv;
        #pragma unroll
        for (int e = 0; e < 8; ++e)
          hv[e] = (_Float16)Wj[(h8 * 8 + e) * 256 + cc];   // column, L2-hot
        out[kt * 1024 + cc * 4 + quad] = hv;
      }
    }
    return;
  }

  // ---- x conversion: block (b = bid>>1, h = bid&1) ----
  const int bid = blockIdx.x;
  const int b = bid >> 1, h = bid & 1;
  const float* xb = x + (size_t)b * 65536;

  // pass A: rows -> x16y
  f16x8* xy8 = reinterpret_cast<f16x8*>(x16y) + (size_t)b * 8192;
  #pragma unroll
  for (int pp = 0; pp < 4; ++pp) {
    const int p = pp * 256 + t;
    const int i8l = (p & 15) * 8;
    const int c4 = (p >> 4) * 4;
    const int ig8 = h * 128 + i8l;
    const int kk = ig8 >> 5, qd = (ig8 >> 3) & 3;
    f32x4 v[4][2];
    #pragma unroll
    for (int s = 0; s < 4; ++s) {
      v[s][0] = *reinterpret_cast<const f32x4*>(&xb[(c4 + s) * 256 + ig8]);
      v[s][1] = *reinterpret_cast<const f32x4*>(&xb[(c4 + s) * 256 + ig8 + 4]);
    }
    #pragma unroll
    for (int s = 0; s < 4; ++s) {
      f16x8 hv;
      #pragma unroll
      for (int e = 0; e < 4; ++e) {
        hv[e] = (_Float16)v[s][0][e];
        hv[4 + e] = (_Float16)v[s][1][e];
      }
      xy8[kk * 1024 + (c4 + s) * 4 + qd] = hv;
    }
  }

  // pass B: columns (L2-hot re-read) -> xTd, coalesced 16B/lane writes
  f16x8* xt8 = reinterpret_cast<f16x8*>(xTd) + (size_t)b * 8192;
  #pragma unroll
  for (int r = 0; r < 16; ++r) {
    const int lv = r * 256 + t;
    const int kt = lv >> 9, s = lv & 511;
    const int il = s >> 2, qd = s & 3;
    const int ig = h * 128 + il;
    const int c0 = kt * 32 + qd * 8;
    f16x8 hv;
    #pragma unroll
    for (int e = 0; e < 8; ++e)
      hv[e] = (_Float16)xb[(c0 + e) * 256 + ig];
    xt8[kt * 1024 + h * 512 + s] = hv;   // == kt*1024 + ig*4 + qd
  }
}

// ---------------------------------------------------------------------------
// kR: grid 256 (block=batch), block 1024 (16 waves). Wave w owns columns
// ii = w*16 + l15 (used as i for routing, as c for the y-GEMM).
// delta B-frag: xTd vec[kt*1024 + ii*4 + quad]  (global, 1KB/wave, L3-hit)
// y     B-frag: x16y vec[kk*1024 + ii*4 + quad] (global, 1KB/wave, L3-hit)
// ---------------------------------------------------------------------------
__global__ __launch_bounds__(1024) void kR(
    const _Float16* __restrict__ x16y,
    const _Float16* __restrict__ xTd,
    const _Float16* __restrict__ u,     // [b][j][c]  (modes 1,2)
    const float* __restrict__ vb,       // [b][j]     (modes 1,2)
    const float* __restrict__ bsrc,     // [b][j][i]  (b_init or b2)
    float* __restrict__ b2out,          // [b][j][i]  (mode 1 writes)
    _Float16* __restrict__ y16,         // [b][j][c]
    float* __restrict__ csum_ws,        // [b][j]
    int mode)
{
  __shared__ __align__(16) _Float16 SB[32 * 264];  // u stage -> y repack
  __shared__ __align__(16) _Float16 cs[32 * 264];  // softmax out
  __shared__ float vbs[32];
  __shared__ float csumsh[32];

  const int b = blockIdx.x, t = threadIdx.x;
  const int w = t >> 6, lane = t & 63, l15 = lane & 15, quad = lane >> 4;
  const int ii = w * 16 + l15;
  const float* bp = bsrc + (size_t)b * 8192;

  if (mode != 0) {
    const f16x8* ug = reinterpret_cast<const f16x8*>(u + (size_t)b * 8192);
    *reinterpret_cast<f16x8*>(&SB[(t >> 5) * 264 + (t & 31) * 8]) = ug[t];
    if (t < 32) vbs[t] = vb[b * 32 + t];
  }
  if (t < 32) csumsh[t] = 0.f;

  // routing logits (coalesced; overlap the u staging)
  float breg[2][4];
  #pragma unroll
  for (int mt = 0; mt < 2; ++mt)
    #pragma unroll
    for (int rr = 0; rr < 4; ++rr)
      breg[mt][rr] = bp[(mt * 16 + quad * 4 + rr) * 256 + ii];

  __syncthreads();  // B1: SB/vbs staged, csumsh zeroed

  if (mode != 0) {
    // ---- delta-GEMM: D[j, ii] = sum_c u[j,c] x[c,ii] ----
    const f16x8* xt8 = reinterpret_cast<const f16x8*>(xTd) + (size_t)b * 8192;
    f32x4 acc0 = (f32x4){0.f, 0.f, 0.f, 0.f};
    f32x4 acc1 = (f32x4){0.f, 0.f, 0.f, 0.f};
    #pragma unroll
    for (int kt = 0; kt < 8; ++kt) {
      const int ko = kt * 32 + quad * 8;
      f16x8 bf = xt8[kt * 1024 + ii * 4 + quad];   // coalesced global (L3)
      f16x8 a0 = *reinterpret_cast<const f16x8*>(&SB[l15 * 264 + ko]);
      f16x8 a1 = *reinterpret_cast<const f16x8*>(&SB[(16 + l15) * 264 + ko]);
      acc0 = __builtin_amdgcn_mfma_f32_16x16x32_f16(a0, bf, acc0, 0, 0, 0);
      acc1 = __builtin_amdgcn_mfma_f32_16x16x32_f16(a1, bf, acc1, 0, 0, 0);
    }
    #pragma unroll
    for (int rr = 0; rr < 4; ++rr) {
      const int j0 = quad * 4 + rr;
      breg[0][rr] += acc0[rr] + vbs[j0];
      breg[1][rr] += acc1[rr] + vbs[16 + j0];
    }
    if (mode == 1) {
      // checkpoint b2 = b_init + D0 + vb0 (fp32, bit-identical to recompute)
      float* bo = b2out + (size_t)b * 8192;
      #pragma unroll
      for (int mt = 0; mt < 2; ++mt)
        #pragma unroll
        for (int rr = 0; rr < 4; ++rr)
          bo[(mt * 16 + quad * 4 + rr) * 256 + ii] = breg[mt][rr];
    }
  }

  // ---- softmax over j (registers + shfl across quads/halves) ----
  float cf[2][4];
  {
    float m = breg[0][0];
    #pragma unroll
    for (int mt = 0; mt < 2; ++mt)
      #pragma unroll
      for (int rr = 0; rr < 4; ++rr) m = fmaxf(m, breg[mt][rr]);
    m = fmaxf(m, __shfl_xor(m, 16));
    m = fmaxf(m, __shfl_xor(m, 32));
    float s = 0.f;
    #pragma unroll
    for (int mt = 0; mt < 2; ++mt)
      #pragma unroll
      for (int rr = 0; rr < 4; ++rr) {
        float e = __expf(breg[mt][rr] - m);
        cf[mt][rr] = e; s += e;
      }
    s += __shfl_xor(s, 16);
    s += __shfl_xor(s, 32);
    const float rinv = 1.f / s;
    #pragma unroll
    for (int mt = 0; mt < 2; ++mt)
      #pragma unroll
      for (int rr = 0; rr < 4; ++rr) {
        const float cv = cf[mt][rr] * rinv;
        cf[mt][rr] = cv;
        cs[(mt * 16 + quad * 4 + rr) * 264 + ii] = (_Float16)cv;
      }
  }
  __syncthreads();  // B2: cs visible; SB u-reads complete

  // csum[j]
  #pragma unroll
  for (int mt = 0; mt < 2; ++mt)
    #pragma unroll
    for (int rr = 0; rr < 4; ++rr) {
      float pj = cf[mt][rr];
      pj += __shfl_xor(pj, 1);
      pj += __shfl_xor(pj, 2);
      pj += __shfl_xor(pj, 4);
      pj += __shfl_xor(pj, 8);
      if (l15 == 0) atomicAdd(&csumsh[mt * 16 + quad * 4 + rr], pj);
    }

  // ---- y[j,c] = sum_i c[j,i] x[c,i]; wave w covers c = ii ----
  {
    const f16x8* xy8 = reinterpret_cast<const f16x8*>(x16y) + (size_t)b * 8192;
    f32x4 acy0 = (f32x4){0.f, 0.f, 0.f, 0.f};
    f32x4 acy1 = (f32x4){0.f, 0.f, 0.f, 0.f};
    #pragma unroll
    for (int kk = 0; kk < 8; ++kk) {
      const int ko = kk * 32 + quad * 8;
      f16x8 bf = xy8[kk * 1024 + ii * 4 + quad];   // coalesced global (L3)
      f16x8 a0 = *reinterpret_cast<const f16x8*>(&cs[l15 * 264 + ko]);
      f16x8 a1 = *reinterpret_cast<const f16x8*>(&cs[(16 + l15) * 264 + ko]);
      acy0 = __builtin_amdgcn_mfma_f32_16x16x32_f16(a0, bf, acy0, 0, 0, 0);
      acy1 = __builtin_amdgcn_mfma_f32_16x16x32_f16(a1, bf, acy1, 0, 0, 0);
    }
    // repack D-layout -> SB (safe: SB u-reads ended at B2; cs untouched)
    #pragma unroll
    for (int rr = 0; rr < 4; ++rr) {
      SB[(quad * 4 + rr) * 264 + ii] = (_Float16)acy0[rr];
      SB[(16 + quad * 4 + rr) * 264 + ii] = (_Float16)acy1[rr];
    }
  }
  __syncthreads();  // B3: repack + csum atomics complete

  *reinterpret_cast<f16x8*>(
      &y16[(size_t)b * 8192 + (t >> 5) * 256 + (t & 31) * 8]) =
      *reinterpret_cast<const f16x8*>(&SB[(t >> 5) * 264 + (t & 31) * 8]);
  if (t < 32) csum_ws[b * 32 + t] = csumsh[t];
}

// ---------------------------------------------------------------------------
// k2: grid 256 = 32 j x 8 chunks of 32 batches, block 512 (8 waves).
// ---------------------------------------------------------------------------
__global__ __launch_bounds__(512) void k2(
    const _Float16* __restrict__ Wy,
    const _Float16* __restrict__ WTd,
    const float* __restrict__ bias,
    const _Float16* __restrict__ y16,   // [b][j][c]
    const float* __restrict__ csum_ws,  // [b][j]
    _Float16* __restrict__ u16,         // [b][j][c] (target buffer)
    float* __restrict__ vb_ws,          // [b][j]
    float* __restrict__ vout,           // [b][j][d]
    int final_iter)
{
  __shared__ __align__(16) _Float16 ysh[32 * 264];   // y stage, then u-repack
  __shared__ __align__(16) _Float16 vsh[32 * 72];
  __shared__ float n2sh[32];
  __shared__ float vbsh[32];
  __shared__ float csums[32];

  const int jb = blockIdx.x & 31;
  const int b0 = (blockIdx.x >> 5) * 32;
  const int t = threadIdx.x;
  const int w = t >> 6, lane = t & 63, l15 = lane & 15, quad = lane >> 4;

  #pragma unroll
  for (int p0 = 0; p0 < 2; ++p0) {
    const int p = p0 * 512 + t;
    const int bs = p >> 5, co = (p & 31) * 8;
    *reinterpret_cast<f16x8*>(&ysh[bs * 264 + co]) =
        *reinterpret_cast<const f16x8*>(
            &y16[(size_t)(b0 + bs) * 8192 + jb * 256 + co]);
  }
  if (t < 32) {
    csums[t] = csum_ws[(b0 + t) * 32 + jb];
    n2sh[t] = 0.f;
    vbsh[t] = 0.f;
  }
  __syncthreads();

  // ---- s-GEMM: wave w -> (mt = w&1, nt = w>>1); W prefetched ----
  const int mt = w & 1, nt = w >> 1;
  const int d = nt * 16 + l15;
  f16x8 wreg[8];
  {
    const f16x8* Wg8 = reinterpret_cast<const f16x8*>(Wy) + (size_t)jb * 2048;
    #pragma unroll
    for (int kt = 0; kt < 8; ++kt) wreg[kt] = Wg8[kt * 256 + d * 4 + quad];
  }
  f32x4 sacc = (f32x4){0.f, 0.f, 0.f, 0.f};
  #pragma unroll
  for (int kt = 0; kt < 8; ++kt) {
    const int ko = kt * 32 + quad * 8;
    f16x8 a = *reinterpret_cast<const f16x8*>(&ysh[(mt * 16 + l15) * 264 + ko]);
    sacc = __builtin_amdgcn_mfma_f32_16x16x32_f16(a, wreg[kt], sacc, 0, 0, 0);
  }
  const float biasd = bias[jb * 64 + d];
  float sv[4];
  #pragma unroll
  for (int rr = 0; rr < 4; ++rr)
    sv[rr] = sacc[rr] + biasd * csums[mt * 16 + quad * 4 + rr];

  #pragma unroll
  for (int rr = 0; rr < 4; ++rr) {
    float p = sv[rr] * sv[rr];
    p += __shfl_xor(p, 1);
    p += __shfl_xor(p, 2);
    p += __shfl_xor(p, 4);
    p += __shfl_xor(p, 8);
    if (l15 == 0) atomicAdd(&n2sh[mt * 16 + quad * 4 + rr], p);
  }
  __syncthreads();

  float vv[4];
  #pragma unroll
  for (int rr = 0; rr < 4; ++rr) {
    const float n2 = n2sh[mt * 16 + quad * 4 + rr];
    const float sc = sqrtf(n2) / (1.f + n2);
    vv[rr] = sv[rr] * sc;
  }

  if (final_iter) {
    #pragma unroll
    for (int rr = 0; rr < 4; ++rr)
      vout[((size_t)(b0 + mt * 16 + quad * 4 + rr) * 32 + jb) * 64 + d] = vv[rr];
  } else {
    #pragma unroll
    for (int rr = 0; rr < 4; ++rr) {
      vsh[(mt * 16 + quad * 4 + rr) * 72 + d] = (_Float16)vv[rr];
      float p = vv[rr] * biasd;
      p += __shfl_xor(p, 1);
      p += __shfl_xor(p, 2);
      p += __shfl_xor(p, 4);
      p += __shfl_xor(p, 8);
      if (l15 == 0) atomicAdd(&vbsh[mt * 16 + quad * 4 + rr], p);
    }
    __syncthreads();   // vsh/vbsh complete; ysh reads done -> reuse ysh
    if (t < 32) vb_ws[(b0 + t) * 32 + jb] = vbsh[t];

    // ---- u-GEMM: wave w -> (mt, ntu = (w>>1)*4 + qx) ----
    const f16x8* WT8 = reinterpret_cast<const f16x8*>(WTd) + (size_t)jb * 2048;
    #pragma unroll
    for (int qx = 0; qx < 4; ++qx) {
      const int ntu = (w >> 1) * 4 + qx;
      const int cc = ntu * 16 + l15;
      f32x4 ua = (f32x4){0.f, 0.f, 0.f, 0.f};
      #pragma unroll
      for (int kt = 0; kt < 2; ++kt) {
        const int ko = kt * 32 + quad * 8;
        f16x8 a =
            *reinterpret_cast<const f16x8*>(&vsh[(mt * 16 + l15) * 72 + ko]);
        f16x8 bf = WT8[kt * 1024 + cc * 4 + quad];   // coalesced (L2)
        ua = __builtin_amdgcn_mfma_f32_16x16x32_f16(a, bf, ua, 0, 0, 0);
      }
      #pragma unroll
      for (int rr = 0; rr < 4; ++rr)
        ysh[(mt * 16 + quad * 4 + rr) * 264 + cc] = (_Float16)ua[rr];
    }
    __syncthreads();
    // coalesced u16 write-out
    #pragma unroll
    for (int p0 = 0; p0 < 2; ++p0) {
      const int p = p0 * 512 + t;
      const int bs = p >> 5, co = (p & 31) * 8;
      *reinterpret_cast<f16x8*>(&u16[(size_t)(b0 + bs) * 8192 + jb * 256 + co]) =
          *reinterpret_cast<const f16x8*>(&ysh[bs * 264 + co]);
    }
  }
}

// ---------------------------------------------------------------------------
extern "C" void kernel_launch(void* const* d_in, const int* in_sizes, int n_in,
                              void* d_out, int out_size, void* d_ws, size_t ws_size,
                              hipStream_t stream) {
  (void)in_sizes; (void)n_in; (void)out_size; (void)ws_size;
  const float* x      = (const float*)d_in[0];
  const float* W      = (const float*)d_in[1];
  const float* bias   = (const float*)d_in[2];
  const float* b_init = (const float*)d_in[3];
  char* ws = (char*)d_ws;

  _Float16* x16y = (_Float16*)(ws);                             // 32 MiB
  _Float16* xTd  = (_Float16*)(ws + (32u << 20));               // 32 MiB
  _Float16* y16  = (_Float16*)(ws + (64u << 20));               // 4 MiB
  _Float16* u16a = (_Float16*)(ws + (68u << 20));               // 4 MiB
  _Float16* u16b = (_Float16*)(ws + (72u << 20));               // 4 MiB
  float*    b2   = (float*)(ws + (76u << 20));                  // 8 MiB
  _Float16* Wy   = (_Float16*)(ws + (84u << 20));               // 1 MiB
  _Float16* WTd  = (_Float16*)(ws + (85u << 20));               // 1 MiB
  float*    csum = (float*)(ws + (86u << 20));                  // 32 KiB
  float*    vb0  = (float*)(ws + (86u << 20) + (32u << 10));    // 32 KiB
  float*    vb1  = (float*)(ws + (86u << 20) + (64u << 10));    // 32 KiB
  float*    vout = (float*)d_out;

  kXW<<<544, 256, 0, stream>>>(x, W, x16y, xTd, Wy, WTd);
  // iter 1: softmax(b_init), y
  kR<<<256, 1024, 0, stream>>>(x16y, xTd, u16a, vb0, b_init, b2, y16, csum, 0);
  k2<<<256, 512, 0, stream>>>(Wy, WTd, bias, y16, csum, u16a, vb0, vout, 0);
  // iter 2: b = b_init + D(u0)+vb0, checkpoint b2
  kR<<<256, 1024, 0, stream>>>(x16y, xTd, u16a, vb0, b_init, b2, y16, csum, 1);
  k2<<<256, 512, 0, stream>>>(Wy, WTd, bias, y16, csum, u16b, vb1, vout, 0);
  // iter 3: b = b2 + D(u1)+vb1 (single delta pass)
  kR<<<256, 1024, 0, stream>>>(x16y, xTd, u16b, vb1, b2, b2, y16, csum, 2);
  k2<<<256, 512, 0, stream>>>(Wy, WTd, bias, y16, csum, u16a, vb0, vout, 1);
}

// Round 6
// 191.320 us; speedup vs baseline: 1.0615x; 1.0117x over previous
//
#include <hip/hip_runtime.h>

// CapsNet dynamic routing — 7 launches, full-occupancy streaming conversion.
//   kXW: blocks 0-2047: (b = bid>>3, p = bid&7) convert x rows
//        [p*32,(p+1)*32) -> x16y frags (pass A) and xTd frags (pass B,
//        L1-hot re-read of the same 32KB). 2048 blocks x 4 waves = full
//        occupancy. Blocks 2048-2079: W fp32 -> Wy + WTd (no LDS).
//   kR:  grid 256 (block=batch), block 1024 (16 waves). No x staging; both
//        GEMMs read B-frags direct from global frag buffers into REGISTER
//        prefetch arrays (dbf before barrier, ybf during softmax) so global
//        latency hides under VALU work. LDS only for u (16KB) + cs (17KB).
//        mode 0: softmax(b_init)+y. mode 1: delta=u0@xT, b=b_init+D0+vb0,
//        checkpoint b2 (fp32), y. mode 2: b=b2+D1+vb1, y.
//   k2:  grid 256 = (j, 32-batch chunk), block 512. Wy AND WTd frags
//        prefetched to regs up front. s-GEMM + bias*csum, squash, then
//        u-GEMM -> u16 (+vb) or vout.

#define BSZ 256

typedef _Float16 f16x8 __attribute__((ext_vector_type(8)));
typedef float f32x4 __attribute__((ext_vector_type(4)));

// ---------------------------------------------------------------------------
// kXW: grid 2080, block 256.
// x16y f16x8 idx (per b, 8192): kk*1024 + c*4 + quad (kk=i>>5, quad=(i>>3)&3,
//   e=i&7)
// xTd  f16x8 idx (per b, 8192): kt*1024 + i*4 + qd  (kt=c>>5, qd=(c>>3)&3,
//   e=c&7)
// Wy  f16x8 idx (per j, 2048): kt*256 + d*4 + quad   (kt=c>>5, e=c&7)
// WTd f16x8 idx (per j, 2048): kt*1024 + cc*4 + quad (kt=d>>5, e=d&7)
// ---------------------------------------------------------------------------
__global__ __launch_bounds__(256) void kXW(
    const float* __restrict__ x,        // [b][c][i] fp32
    const float* __restrict__ W,        // [32*64][256] fp32
    _Float16* __restrict__ x16y,
    _Float16* __restrict__ xTd,
    _Float16* __restrict__ Wy,
    _Float16* __restrict__ WTd)
{
  const int t = threadIdx.x;

  if (blockIdx.x >= 2048) {
    // ---- W prep (no LDS): j = blockIdx.x - 2048 ----
    const int j = blockIdx.x - 2048;
    const float* Wj = W + (size_t)j * 64 * 256;
    {
      const int d = t & 63, quad = t >> 6;
      f16x8* out = reinterpret_cast<f16x8*>(Wy) + (size_t)j * 2048;
      #pragma unroll
      for (int kt = 0; kt < 8; ++kt) {
        const int c0 = kt * 32 + quad * 8;
        f32x4 v0 = *reinterpret_cast<const f32x4*>(&Wj[d * 256 + c0]);
        f32x4 v1 = *reinterpret_cast<const f32x4*>(&Wj[d * 256 + c0 + 4]);
        f16x8 hv;
        #pragma unroll
        for (int e = 0; e < 4; ++e) {
          hv[e] = (_Float16)v0[e];
          hv[4 + e] = (_Float16)v1[e];
        }
        out[kt * 256 + d * 4 + quad] = hv;
      }
    }
    {
      const int cc = t;
      f16x8* out = reinterpret_cast<f16x8*>(WTd) + (size_t)j * 2048;
      #pragma unroll
      for (int h8 = 0; h8 < 8; ++h8) {
        const int kt = h8 >> 2, quad = h8 & 3;
        f16x8 hv;
        #pragma unroll
        for (int e = 0; e < 8; ++e)
          hv[e] = (_Float16)Wj[(h8 * 8 + e) * 256 + cc];   // column, L2-hot
        out[kt * 1024 + cc * 4 + quad] = hv;
      }
    }
    return;
  }

  // ---- x conversion: block (b = bid>>3, p = bid&7), c rows [p*32,p*32+32) --
  const int bid = blockIdx.x;
  const int b = bid >> 3, p = bid & 7;
  const float* xb = x + (size_t)b * 65536;

  // pass A: rows -> x16y (one 4c x 8i tile per thread)
  {
    f16x8* xy8 = reinterpret_cast<f16x8*>(x16y) + (size_t)b * 8192;
    const int it = t & 31, cg = t >> 5;
    const int i8 = it * 8;
    const int c4 = p * 32 + cg * 4;
    const int kk = i8 >> 5, qd = (i8 >> 3) & 3;
    f32x4 v[4][2];
    #pragma unroll
    for (int s = 0; s < 4; ++s) {
      v[s][0] = *reinterpret_cast<const f32x4*>(&xb[(c4 + s) * 256 + i8]);
      v[s][1] = *reinterpret_cast<const f32x4*>(&xb[(c4 + s) * 256 + i8 + 4]);
    }
    #pragma unroll
    for (int s = 0; s < 4; ++s) {
      f16x8 hv;
      #pragma unroll
      for (int e = 0; e < 4; ++e) {
        hv[e] = (_Float16)v[s][0][e];
        hv[4 + e] = (_Float16)v[s][1][e];
      }
      xy8[kk * 1024 + (c4 + s) * 4 + qd] = hv;
    }
  }

  // pass B: same 32 rows, column-order (L1-hot) -> xTd, 64B/thread writes
  {
    f16x8* xt8 = reinterpret_cast<f16x8*>(xTd) + (size_t)b * 8192;
    const int ig = t;   // i column
    #pragma unroll
    for (int qd = 0; qd < 4; ++qd) {
      const int c0 = p * 32 + qd * 8;
      f16x8 hv;
      #pragma unroll
      for (int e = 0; e < 8; ++e)
        hv[e] = (_Float16)xb[(c0 + e) * 256 + ig];
      xt8[p * 1024 + ig * 4 + qd] = hv;
    }
  }
}

// ---------------------------------------------------------------------------
// kR: grid 256 (block=batch), block 1024 (16 waves). Wave w owns columns
// ii = w*16 + l15 (used as i for routing, as c for the y-GEMM).
// delta B-frag: xTd vec[kt*1024 + ii*4 + quad]  -> dbf regs (pre-B1)
// y     B-frag: x16y vec[kk*1024 + ii*4 + quad] -> ybf regs (pre-softmax)
// ---------------------------------------------------------------------------
__global__ __launch_bounds__(1024) void kR(
    const _Float16* __restrict__ x16y,
    const _Float16* __restrict__ xTd,
    const _Float16* __restrict__ u,     // [b][j][c]  (modes 1,2)
    const float* __restrict__ vb,       // [b][j]     (modes 1,2)
    const float* __restrict__ bsrc,     // [b][j][i]  (b_init or b2)
    float* __restrict__ b2out,          // [b][j][i]  (mode 1 writes)
    _Float16* __restrict__ y16,         // [b][j][c]
    float* __restrict__ csum_ws,        // [b][j]
    int mode)
{
  __shared__ __align__(16) _Float16 SB[32 * 264];  // u stage -> y repack
  __shared__ __align__(16) _Float16 cs[32 * 264];  // softmax out
  __shared__ float vbs[32];
  __shared__ float csumsh[32];

  const int b = blockIdx.x, t = threadIdx.x;
  const int w = t >> 6, lane = t & 63, l15 = lane & 15, quad = lane >> 4;
  const int ii = w * 16 + l15;
  const float* bp = bsrc + (size_t)b * 8192;
  const f16x8* xy8 = reinterpret_cast<const f16x8*>(x16y) + (size_t)b * 8192;

  if (mode != 0) {
    const f16x8* ug = reinterpret_cast<const f16x8*>(u + (size_t)b * 8192);
    *reinterpret_cast<f16x8*>(&SB[(t >> 5) * 264 + (t & 31) * 8]) = ug[t];
    if (t < 32) vbs[t] = vb[b * 32 + t];
  }
  if (t < 32) csumsh[t] = 0.f;

  // routing logits (coalesced; overlap the u staging)
  float breg[2][4];
  #pragma unroll
  for (int mt = 0; mt < 2; ++mt)
    #pragma unroll
    for (int rr = 0; rr < 4; ++rr)
      breg[mt][rr] = bp[(mt * 16 + quad * 4 + rr) * 256 + ii];

  // prefetch delta B-frags to registers BEFORE the barrier (indep of LDS)
  f16x8 dbf[8];
  if (mode != 0) {
    const f16x8* xt8 = reinterpret_cast<const f16x8*>(xTd) + (size_t)b * 8192;
    #pragma unroll
    for (int kt = 0; kt < 8; ++kt)
      dbf[kt] = xt8[kt * 1024 + ii * 4 + quad];
  }

  __syncthreads();  // B1: SB/vbs staged, csumsh zeroed

  if (mode != 0) {
    // ---- delta-GEMM: D[j, ii] = sum_c u[j,c] x[c,ii] (B in regs) ----
    f32x4 acc0 = (f32x4){0.f, 0.f, 0.f, 0.f};
    f32x4 acc1 = (f32x4){0.f, 0.f, 0.f, 0.f};
    #pragma unroll
    for (int kt = 0; kt < 8; ++kt) {
      const int ko = kt * 32 + quad * 8;
      f16x8 a0 = *reinterpret_cast<const f16x8*>(&SB[l15 * 264 + ko]);
      f16x8 a1 = *reinterpret_cast<const f16x8*>(&SB[(16 + l15) * 264 + ko]);
      acc0 = __builtin_amdgcn_mfma_f32_16x16x32_f16(a0, dbf[kt], acc0, 0, 0, 0);
      acc1 = __builtin_amdgcn_mfma_f32_16x16x32_f16(a1, dbf[kt], acc1, 0, 0, 0);
    }
    #pragma unroll
    for (int rr = 0; rr < 4; ++rr) {
      const int j0 = quad * 4 + rr;
      breg[0][rr] += acc0[rr] + vbs[j0];
      breg[1][rr] += acc1[rr] + vbs[16 + j0];
    }
  }

  // prefetch y B-frags; latency hides under b2 store + softmax VALU
  f16x8 ybf[8];
  #pragma unroll
  for (int kk = 0; kk < 8; ++kk)
    ybf[kk] = xy8[kk * 1024 + ii * 4 + quad];

  if (mode == 1) {
    // checkpoint b2 = b_init + D0 + vb0 (fp32, bit-identical to recompute)
    float* bo = b2out + (size_t)b * 8192;
    #pragma unroll
    for (int mt = 0; mt < 2; ++mt)
      #pragma unroll
      for (int rr = 0; rr < 4; ++rr)
        bo[(mt * 16 + quad * 4 + rr) * 256 + ii] = breg[mt][rr];
  }

  // ---- softmax over j (registers + shfl across quads/halves) ----
  float cf[2][4];
  {
    float m = breg[0][0];
    #pragma unroll
    for (int mt = 0; mt < 2; ++mt)
      #pragma unroll
      for (int rr = 0; rr < 4; ++rr) m = fmaxf(m, breg[mt][rr]);
    m = fmaxf(m, __shfl_xor(m, 16));
    m = fmaxf(m, __shfl_xor(m, 32));
    float s = 0.f;
    #pragma unroll
    for (int mt = 0; mt < 2; ++mt)
      #pragma unroll
      for (int rr = 0; rr < 4; ++rr) {
        float e = __expf(breg[mt][rr] - m);
        cf[mt][rr] = e; s += e;
      }
    s += __shfl_xor(s, 16);
    s += __shfl_xor(s, 32);
    const float rinv = 1.f / s;
    #pragma unroll
    for (int mt = 0; mt < 2; ++mt)
      #pragma unroll
      for (int rr = 0; rr < 4; ++rr) {
        const float cv = cf[mt][rr] * rinv;
        cf[mt][rr] = cv;
        cs[(mt * 16 + quad * 4 + rr) * 264 + ii] = (_Float16)cv;
      }
  }
  __syncthreads();  // B2: cs visible; SB u-reads complete

  // csum[j]
  #pragma unroll
  for (int mt = 0; mt < 2; ++mt)
    #pragma unroll
    for (int rr = 0; rr < 4; ++rr) {
      float pj = cf[mt][rr];
      pj += __shfl_xor(pj, 1);
      pj += __shfl_xor(pj, 2);
      pj += __shfl_xor(pj, 4);
      pj += __shfl_xor(pj, 8);
      if (l15 == 0) atomicAdd(&csumsh[mt * 16 + quad * 4 + rr], pj);
    }

  // ---- y[j,c] = sum_i c[j,i] x[c,i]; wave w covers c = ii (B in regs) ----
  {
    f32x4 acy0 = (f32x4){0.f, 0.f, 0.f, 0.f};
    f32x4 acy1 = (f32x4){0.f, 0.f, 0.f, 0.f};
    #pragma unroll
    for (int kk = 0; kk < 8; ++kk) {
      const int ko = kk * 32 + quad * 8;
      f16x8 a0 = *reinterpret_cast<const f16x8*>(&cs[l15 * 264 + ko]);
      f16x8 a1 = *reinterpret_cast<const f16x8*>(&cs[(16 + l15) * 264 + ko]);
      acy0 = __builtin_amdgcn_mfma_f32_16x16x32_f16(a0, ybf[kk], acy0, 0, 0, 0);
      acy1 = __builtin_amdgcn_mfma_f32_16x16x32_f16(a1, ybf[kk], acy1, 0, 0, 0);
    }
    // repack D-layout -> SB (safe: SB u-reads ended at B2; cs untouched)
    #pragma unroll
    for (int rr = 0; rr < 4; ++rr) {
      SB[(quad * 4 + rr) * 264 + ii] = (_Float16)acy0[rr];
      SB[(16 + quad * 4 + rr) * 264 + ii] = (_Float16)acy1[rr];
    }
  }
  __syncthreads();  // B3: repack + csum atomics complete

  *reinterpret_cast<f16x8*>(
      &y16[(size_t)b * 8192 + (t >> 5) * 256 + (t & 31) * 8]) =
      *reinterpret_cast<const f16x8*>(&SB[(t >> 5) * 264 + (t & 31) * 8]);
  if (t < 32) csum_ws[b * 32 + t] = csumsh[t];
}

// ---------------------------------------------------------------------------
// k2: grid 256 = 32 j x 8 chunks of 32 batches, block 512 (8 waves).
// ---------------------------------------------------------------------------
__global__ __launch_bounds__(512) void k2(
    const _Float16* __restrict__ Wy,
    const _Float16* __restrict__ WTd,
    const float* __restrict__ bias,
    const _Float16* __restrict__ y16,   // [b][j][c]
    const float* __restrict__ csum_ws,  // [b][j]
    _Float16* __restrict__ u16,         // [b][j][c] (target buffer)
    float* __restrict__ vb_ws,          // [b][j]
    float* __restrict__ vout,           // [b][j][d]
    int final_iter)
{
  __shared__ __align__(16) _Float16 ysh[32 * 264];   // y stage, then u-repack
  __shared__ __align__(16) _Float16 vsh[32 * 72];
  __shared__ float n2sh[32];
  __shared__ float vbsh[32];
  __shared__ float csums[32];

  const int jb = blockIdx.x & 31;
  const int b0 = (blockIdx.x >> 5) * 32;
  const int t = threadIdx.x;
  const int w = t >> 6, lane = t & 63, l15 = lane & 15, quad = lane >> 4;
  const int mt = w & 1, nt = w >> 1;
  const int d = nt * 16 + l15;

  // prefetch ALL W fragments up front (latency hides under y staging)
  f16x8 wreg[8];
  {
    const f16x8* Wg8 = reinterpret_cast<const f16x8*>(Wy) + (size_t)jb * 2048;
    #pragma unroll
    for (int kt = 0; kt < 8; ++kt) wreg[kt] = Wg8[kt * 256 + d * 4 + quad];
  }
  f16x8 wt8r[8];
  if (!final_iter) {
    const f16x8* WT8 = reinterpret_cast<const f16x8*>(WTd) + (size_t)jb * 2048;
    #pragma unroll
    for (int qx = 0; qx < 4; ++qx) {
      const int cc = ((w >> 1) * 4 + qx) * 16 + l15;
      #pragma unroll
      for (int kt = 0; kt < 2; ++kt)
        wt8r[qx * 2 + kt] = WT8[kt * 1024 + cc * 4 + quad];
    }
  }

  #pragma unroll
  for (int p0 = 0; p0 < 2; ++p0) {
    const int p = p0 * 512 + t;
    const int bs = p >> 5, co = (p & 31) * 8;
    *reinterpret_cast<f16x8*>(&ysh[bs * 264 + co]) =
        *reinterpret_cast<const f16x8*>(
            &y16[(size_t)(b0 + bs) * 8192 + jb * 256 + co]);
  }
  if (t < 32) {
    csums[t] = csum_ws[(b0 + t) * 32 + jb];
    n2sh[t] = 0.f;
    vbsh[t] = 0.f;
  }
  __syncthreads();

  // ---- s-GEMM: wave w -> (mt, nt) ----
  f32x4 sacc = (f32x4){0.f, 0.f, 0.f, 0.f};
  #pragma unroll
  for (int kt = 0; kt < 8; ++kt) {
    const int ko = kt * 32 + quad * 8;
    f16x8 a = *reinterpret_cast<const f16x8*>(&ysh[(mt * 16 + l15) * 264 + ko]);
    sacc = __builtin_amdgcn_mfma_f32_16x16x32_f16(a, wreg[kt], sacc, 0, 0, 0);
  }
  const float biasd = bias[jb * 64 + d];
  float sv[4];
  #pragma unroll
  for (int rr = 0; rr < 4; ++rr)
    sv[rr] = sacc[rr] + biasd * csums[mt * 16 + quad * 4 + rr];

  #pragma unroll
  for (int rr = 0; rr < 4; ++rr) {
    float p = sv[rr] * sv[rr];
    p += __shfl_xor(p, 1);
    p += __shfl_xor(p, 2);
    p += __shfl_xor(p, 4);
    p += __shfl_xor(p, 8);
    if (l15 == 0) atomicAdd(&n2sh[mt * 16 + quad * 4 + rr], p);
  }
  __syncthreads();

  float vv[4];
  #pragma unroll
  for (int rr = 0; rr < 4; ++rr) {
    const float n2 = n2sh[mt * 16 + quad * 4 + rr];
    const float sc = sqrtf(n2) / (1.f + n2);
    vv[rr] = sv[rr] * sc;
  }

  if (final_iter) {
    #pragma unroll
    for (int rr = 0; rr < 4; ++rr)
      vout[((size_t)(b0 + mt * 16 + quad * 4 + rr) * 32 + jb) * 64 + d] = vv[rr];
  } else {
    #pragma unroll
    for (int rr = 0; rr < 4; ++rr) {
      vsh[(mt * 16 + quad * 4 + rr) * 72 + d] = (_Float16)vv[rr];
      float p = vv[rr] * biasd;
      p += __shfl_xor(p, 1);
      p += __shfl_xor(p, 2);
      p += __shfl_xor(p, 4);
      p += __shfl_xor(p, 8);
      if (l15 == 0) atomicAdd(&vbsh[mt * 16 + quad * 4 + rr], p);
    }
    __syncthreads();   // vsh/vbsh complete; ysh reads done -> reuse ysh
    if (t < 32) vb_ws[(b0 + t) * 32 + jb] = vbsh[t];

    // ---- u-GEMM: wave w -> (mt, ntu = (w>>1)*4 + qx), W in regs ----
    #pragma unroll
    for (int qx = 0; qx < 4; ++qx) {
      const int cc = ((w >> 1) * 4 + qx) * 16 + l15;
      f32x4 ua = (f32x4){0.f, 0.f, 0.f, 0.f};
      #pragma unroll
      for (int kt = 0; kt < 2; ++kt) {
        const int ko = kt * 32 + quad * 8;
        f16x8 a =
            *reinterpret_cast<const f16x8*>(&vsh[(mt * 16 + l15) * 72 + ko]);
        ua = __builtin_amdgcn_mfma_f32_16x16x32_f16(a, wt8r[qx * 2 + kt], ua, 0, 0, 0);
      }
      #pragma unroll
      for (int rr = 0; rr < 4; ++rr)
        ysh[(mt * 16 + quad * 4 + rr) * 264 + cc] = (_Float16)ua[rr];
    }
    __syncthreads();
    // coalesced u16 write-out
    #pragma unroll
    for (int p0 = 0; p0 < 2; ++p0) {
      const int p = p0 * 512 + t;
      const int bs = p >> 5, co = (p & 31) * 8;
      *reinterpret_cast<f16x8*>(&u16[(size_t)(b0 + bs) * 8192 + jb * 256 + co]) =
          *reinterpret_cast<const f16x8*>(&ysh[bs * 264 + co]);
    }
  }
}

// ---------------------------------------------------------------------------
extern "C" void kernel_launch(void* const* d_in, const int* in_sizes, int n_in,
                              void* d_out, int out_size, void* d_ws, size_t ws_size,
                              hipStream_t stream) {
  (void)in_sizes; (void)n_in; (void)out_size; (void)ws_size;
  const float* x      = (const float*)d_in[0];
  const float* W      = (const float*)d_in[1];
  const float* bias   = (const float*)d_in[2];
  const float* b_init = (const float*)d_in[3];
  char* ws = (char*)d_ws;

  _Float16* x16y = (_Float16*)(ws);                             // 32 MiB
  _Float16* xTd  = (_Float16*)(ws + (32u << 20));               // 32 MiB
  _Float16* y16  = (_Float16*)(ws + (64u << 20));               // 4 MiB
  _Float16* u16a = (_Float16*)(ws + (68u << 20));               // 4 MiB
  _Float16* u16b = (_Float16*)(ws + (72u << 20));               // 4 MiB
  float*    b2   = (float*)(ws + (76u << 20));                  // 8 MiB
  _Float16* Wy   = (_Float16*)(ws + (84u << 20));               // 1 MiB
  _Float16* WTd  = (_Float16*)(ws + (85u << 20));               // 1 MiB
  float*    csum = (float*)(ws + (86u << 20));                  // 32 KiB
  float*    vb0  = (float*)(ws + (86u << 20) + (32u << 10));    // 32 KiB
  float*    vb1  = (float*)(ws + (86u << 20) + (64u << 10));    // 32 KiB
  float*    vout = (float*)d_out;

  kXW<<<2080, 256, 0, stream>>>(x, W, x16y, xTd, Wy, WTd);
  // iter 1: softmax(b_init), y
  kR<<<256, 1024, 0, stream>>>(x16y, xTd, u16a, vb0, b_init, b2, y16, csum, 0);
  k2<<<256, 512, 0, stream>>>(Wy, WTd, bias, y16, csum, u16a, vb0, vout, 0);
  // iter 2: b = b_init + D(u0)+vb0, checkpoint b2
  kR<<<256, 1024, 0, stream>>>(x16y, xTd, u16a, vb0, b_init, b2, y16, csum, 1);
  k2<<<256, 512, 0, stream>>>(Wy, WTd, bias, y16, csum, u16b, vb1, vout, 0);
  // iter 3: b = b2 + D(u1)+vb1 (single delta pass)
  kR<<<256, 1024, 0, stream>>>(x16y, xTd, u16b, vb1, b2, b2, y16, csum, 2);
  k2<<<256, 512, 0, stream>>>(Wy, WTd, bias, y16, csum, u16a, vb0, vout, 1);
}

// Round 7
// 188.748 us; speedup vs baseline: 1.0760x; 1.0136x over previous
//
#include <hip/hip_runtime.h>

// CapsNet dynamic routing — 7 launches.
//   kXW: blocks 0-2047: (b=bid>>3, p=bid&7) convert x rows [p*32,p*32+32)
//        -> x16y (pass A) + xTd (pass B, L1-hot re-read). Both passes use
//        wave-contiguous stores: each wave-store = 64 consecutive f16x8
//        vecs (vec = base + lane), 1KB/instr. Blocks 2048-2079: W prep.
//   kR:  grid 256 (block=batch), block 1024 (16 waves). NO staging LDS:
//        u A-frags per-wave from global (L1 broadcast), x B-frags from
//        frag buffers into regs (dbf/ybf), y stored direct from accs.
//        2 barriers only (csum init + cs visibility).
//        mode 0: softmax(b_init)+y. mode 1: delta=u0@xT, b=b_init+D0+vb0,
//        checkpoint b2 (fp32), y. mode 2: b=b2+D1+vb1, y.
//   k2:  grid 256 = (j, 32-batch chunk), block 512. Wy+WTd prefetched to
//        regs. s-GEMM + bias*csum, squash, u-GEMM -> u16 (+vb) or vout.

#define BSZ 256

typedef _Float16 f16x8 __attribute__((ext_vector_type(8)));
typedef float f32x4 __attribute__((ext_vector_type(4)));

// ---------------------------------------------------------------------------
// kXW: grid 2080, block 256.
// x16y f16x8 idx (per b, 8192): kk*1024 + c*4 + qd (kk=i>>5, qd=(i>>3)&3,
//   e=i&7)
// xTd  f16x8 idx (per b, 8192): kt*1024 + i*4 + qd (kt=c>>5, qd=(c>>3)&3,
//   e=c&7)
// Wy  f16x8 idx (per j, 2048): kt*256 + d*4 + quad   (kt=c>>5, e=c&7)
// WTd f16x8 idx (per j, 2048): kt*1024 + cc*4 + quad (kt=d>>5, e=d&7)
// ---------------------------------------------------------------------------
__global__ __launch_bounds__(256) void kXW(
    const float* __restrict__ x,        // [b][c][i] fp32
    const float* __restrict__ W,        // [32*64][256] fp32
    _Float16* __restrict__ x16y,
    _Float16* __restrict__ xTd,
    _Float16* __restrict__ Wy,
    _Float16* __restrict__ WTd)
{
  const int t = threadIdx.x;

  if (blockIdx.x >= 2048) {
    // ---- W prep (no LDS): j = blockIdx.x - 2048 ----
    const int j = blockIdx.x - 2048;
    const float* Wj = W + (size_t)j * 64 * 256;
    {
      const int d = t & 63, quad = t >> 6;
      f16x8* out = reinterpret_cast<f16x8*>(Wy) + (size_t)j * 2048;
      #pragma unroll
      for (int kt = 0; kt < 8; ++kt) {
        const int c0 = kt * 32 + quad * 8;
        f32x4 v0 = *reinterpret_cast<const f32x4*>(&Wj[d * 256 + c0]);
        f32x4 v1 = *reinterpret_cast<const f32x4*>(&Wj[d * 256 + c0 + 4]);
        f16x8 hv;
        #pragma unroll
        for (int e = 0; e < 4; ++e) {
          hv[e] = (_Float16)v0[e];
          hv[4 + e] = (_Float16)v1[e];
        }
        out[kt * 256 + d * 4 + quad] = hv;
      }
    }
    {
      const int cc = t;
      f16x8* out = reinterpret_cast<f16x8*>(WTd) + (size_t)j * 2048;
      #pragma unroll
      for (int h8 = 0; h8 < 8; ++h8) {
        const int kt = h8 >> 2, quad = h8 & 3;
        f16x8 hv;
        #pragma unroll
        for (int e = 0; e < 8; ++e)
          hv[e] = (_Float16)Wj[(h8 * 8 + e) * 256 + cc];   // column, L2-hot
        out[kt * 1024 + cc * 4 + quad] = hv;
      }
    }
    return;
  }

  // ---- x conversion: block (b = bid>>3, p = bid&7), c rows [p*32,p*32+32) --
  const int bid = blockIdx.x;
  const int b = bid >> 3, p = bid & 7;
  const float* xb = x + (size_t)b * 65536;
  const int w = t >> 6, l = t & 63;

  // pass A: rows -> x16y. 16 tasks (kk,cH); wave-store = 64 consecutive vecs.
  {
    f16x8* xy8 = reinterpret_cast<f16x8*>(x16y) + (size_t)b * 8192;
    #pragma unroll
    for (int step = 0; step < 4; ++step) {
      const int tk = step * 4 + w;
      const int kk = tk >> 1, cH = tk & 1;
      const int c = p * 32 + cH * 16 + (l >> 2);
      const int qd = l & 3;
      const int i8 = kk * 32 + qd * 8;
      f32x4 v0 = *reinterpret_cast<const f32x4*>(&xb[c * 256 + i8]);
      f32x4 v1 = *reinterpret_cast<const f32x4*>(&xb[c * 256 + i8 + 4]);
      f16x8 hv;
      #pragma unroll
      for (int e = 0; e < 4; ++e) {
        hv[e] = (_Float16)v0[e];
        hv[4 + e] = (_Float16)v1[e];
      }
      xy8[kk * 1024 + c * 4 + qd] = hv;   // vec = base + lane: 1KB/wave
    }
  }

  // pass B: same 32 rows, column-order (L1-hot) -> xTd (kt == p exactly).
  {
    f16x8* xt8 = reinterpret_cast<f16x8*>(xTd) + (size_t)b * 8192;
    #pragma unroll
    for (int step = 0; step < 4; ++step) {
      const int tk = step * 4 + w;
      const int ig = tk * 16 + (l >> 2);
      const int qd = l & 3;
      const int c0 = p * 32 + qd * 8;
      f16x8 hv;
      #pragma unroll
      for (int e = 0; e < 8; ++e)
        hv[e] = (_Float16)xb[(c0 + e) * 256 + ig];
      xt8[p * 1024 + ig * 4 + qd] = hv;   // vec = base + lane: 1KB/wave
    }
  }
}

// ---------------------------------------------------------------------------
// kR: grid 256 (block=batch), block 1024 (16 waves). Wave w owns columns
// ii = w*16 + l15 (i for routing, c for the y-GEMM). LDS = cs only.
// delta B-frag: xTd vec[kt*1024 + ii*4 + quad]  -> dbf regs
// y     B-frag: x16y vec[kk*1024 + ii*4 + quad] -> ybf regs
// u A-frags read per-wave direct from global (identical across waves -> L1)
// ---------------------------------------------------------------------------
__global__ __launch_bounds__(1024) void kR(
    const _Float16* __restrict__ x16y,
    const _Float16* __restrict__ xTd,
    const _Float16* __restrict__ u,     // [b][j][c]  (modes 1,2)
    const float* __restrict__ vb,       // [b][j]     (modes 1,2)
    const float* __restrict__ bsrc,     // [b][j][i]  (b_init or b2)
    float* __restrict__ b2out,          // [b][j][i]  (mode 1 writes)
    _Float16* __restrict__ y16,         // [b][j][c]
    float* __restrict__ csum_ws,        // [b][j]
    int mode)
{
  __shared__ __align__(16) _Float16 cs[32 * 264];  // softmax out
  __shared__ float csumsh[32];

  const int b = blockIdx.x, t = threadIdx.x;
  const int w = t >> 6, lane = t & 63, l15 = lane & 15, quad = lane >> 4;
  const int ii = w * 16 + l15;
  const float* bp = bsrc + (size_t)b * 8192;
  const f16x8* xy8 = reinterpret_cast<const f16x8*>(x16y) + (size_t)b * 8192;

  if (t < 32) csumsh[t] = 0.f;
  __syncthreads();  // B0: trivial (no memory waits before it)

  // routing logits (coalesced)
  float breg[2][4];
  #pragma unroll
  for (int mt = 0; mt < 2; ++mt)
    #pragma unroll
    for (int rr = 0; rr < 4; ++rr)
      breg[mt][rr] = bp[(mt * 16 + quad * 4 + rr) * 256 + ii];

  f16x8 ybf[8];
  if (mode != 0) {
    // prefetch delta B-frags to regs
    f16x8 dbf[8];
    {
      const f16x8* xt8 = reinterpret_cast<const f16x8*>(xTd) + (size_t)b * 8192;
      #pragma unroll
      for (int kt = 0; kt < 8; ++kt)
        dbf[kt] = xt8[kt * 1024 + ii * 4 + quad];
    }
    // ---- delta-GEMM: D[j, ii] = sum_c u[j,c] x[c,ii] ----
    // A-frags direct from global u (16KB/batch, L1-broadcast across waves)
    const _Float16* ug = u + (size_t)b * 8192;
    f32x4 acc0 = (f32x4){0.f, 0.f, 0.f, 0.f};
    f32x4 acc1 = (f32x4){0.f, 0.f, 0.f, 0.f};
    #pragma unroll
    for (int kt = 0; kt < 8; ++kt) {
      const int ko = kt * 32 + quad * 8;
      f16x8 a0 = *reinterpret_cast<const f16x8*>(&ug[l15 * 256 + ko]);
      f16x8 a1 = *reinterpret_cast<const f16x8*>(&ug[(16 + l15) * 256 + ko]);
      acc0 = __builtin_amdgcn_mfma_f32_16x16x32_f16(a0, dbf[kt], acc0, 0, 0, 0);
      acc1 = __builtin_amdgcn_mfma_f32_16x16x32_f16(a1, dbf[kt], acc1, 0, 0, 0);
    }
    #pragma unroll
    for (int rr = 0; rr < 4; ++rr) {
      const int j0 = quad * 4 + rr;
      breg[0][rr] += acc0[rr] + vb[b * 32 + j0];        // broadcast loads
      breg[1][rr] += acc1[rr] + vb[b * 32 + 16 + j0];
    }
    // prefetch y B-frags; latency hides under b2 store + softmax VALU
    #pragma unroll
    for (int kk = 0; kk < 8; ++kk)
      ybf[kk] = xy8[kk * 1024 + ii * 4 + quad];
    if (mode == 1) {
      // checkpoint b2 = b_init + D0 + vb0 (fp32, bit-identical to recompute)
      float* bo = b2out + (size_t)b * 8192;
      #pragma unroll
      for (int mt = 0; mt < 2; ++mt)
        #pragma unroll
        for (int rr = 0; rr < 4; ++rr)
          bo[(mt * 16 + quad * 4 + rr) * 256 + ii] = breg[mt][rr];
    }
  } else {
    #pragma unroll
    for (int kk = 0; kk < 8; ++kk)
      ybf[kk] = xy8[kk * 1024 + ii * 4 + quad];
  }

  // ---- softmax over j (registers + shfl across quads/halves) ----
  float cf[2][4];
  {
    float m = breg[0][0];
    #pragma unroll
    for (int mt = 0; mt < 2; ++mt)
      #pragma unroll
      for (int rr = 0; rr < 4; ++rr) m = fmaxf(m, breg[mt][rr]);
    m = fmaxf(m, __shfl_xor(m, 16));
    m = fmaxf(m, __shfl_xor(m, 32));
    float s = 0.f;
    #pragma unroll
    for (int mt = 0; mt < 2; ++mt)
      #pragma unroll
      for (int rr = 0; rr < 4; ++rr) {
        float e = __expf(breg[mt][rr] - m);
        cf[mt][rr] = e; s += e;
      }
    s += __shfl_xor(s, 16);
    s += __shfl_xor(s, 32);
    const float rinv = 1.f / s;
    #pragma unroll
    for (int mt = 0; mt < 2; ++mt)
      #pragma unroll
      for (int rr = 0; rr < 4; ++rr) {
        const float cv = cf[mt][rr] * rinv;
        cf[mt][rr] = cv;
        cs[(mt * 16 + quad * 4 + rr) * 264 + ii] = (_Float16)cv;
      }
  }

  // csum[j] (atomics BEFORE the barrier; init done at B0)
  #pragma unroll
  for (int mt = 0; mt < 2; ++mt)
    #pragma unroll
    for (int rr = 0; rr < 4; ++rr) {
      float pj = cf[mt][rr];
      pj += __shfl_xor(pj, 1);
      pj += __shfl_xor(pj, 2);
      pj += __shfl_xor(pj, 4);
      pj += __shfl_xor(pj, 8);
      if (l15 == 0) atomicAdd(&csumsh[mt * 16 + quad * 4 + rr], pj);
    }

  __syncthreads();  // B2: cs + csum atomics visible

  // ---- y[j,c] = sum_i c[j,i] x[c,i]; wave w covers c = ii (B in regs) ----
  {
    f32x4 acy0 = (f32x4){0.f, 0.f, 0.f, 0.f};
    f32x4 acy1 = (f32x4){0.f, 0.f, 0.f, 0.f};
    #pragma unroll
    for (int kk = 0; kk < 8; ++kk) {
      const int ko = kk * 32 + quad * 8;
      f16x8 a0 = *reinterpret_cast<const f16x8*>(&cs[l15 * 264 + ko]);
      f16x8 a1 = *reinterpret_cast<const f16x8*>(&cs[(16 + l15) * 264 + ko]);
      acy0 = __builtin_amdgcn_mfma_f32_16x16x32_f16(a0, ybf[kk], acy0, 0, 0, 0);
      acy1 = __builtin_amdgcn_mfma_f32_16x16x32_f16(a1, ybf[kk], acy1, 0, 0, 0);
    }
    // direct stores (row j = quad*4+rr / 16+..., col c = ii); L2 merges
    _Float16* yo = y16 + (size_t)b * 8192;
    #pragma unroll
    for (int rr = 0; rr < 4; ++rr) {
      yo[(quad * 4 + rr) * 256 + ii] = (_Float16)acy0[rr];
      yo[(16 + quad * 4 + rr) * 256 + ii] = (_Float16)acy1[rr];
    }
  }
  if (t < 32) csum_ws[b * 32 + t] = csumsh[t];
}

// ---------------------------------------------------------------------------
// k2: grid 256 = 32 j x 8 chunks of 32 batches, block 512 (8 waves).
// ---------------------------------------------------------------------------
__global__ __launch_bounds__(512) void k2(
    const _Float16* __restrict__ Wy,
    const _Float16* __restrict__ WTd,
    const float* __restrict__ bias,
    const _Float16* __restrict__ y16,   // [b][j][c]
    const float* __restrict__ csum_ws,  // [b][j]
    _Float16* __restrict__ u16,         // [b][j][c] (target buffer)
    float* __restrict__ vb_ws,          // [b][j]
    float* __restrict__ vout,           // [b][j][d]
    int final_iter)
{
  __shared__ __align__(16) _Float16 ysh[32 * 264];   // y stage, then u-repack
  __shared__ __align__(16) _Float16 vsh[32 * 72];
  __shared__ float n2sh[32];
  __shared__ float vbsh[32];
  __shared__ float csums[32];

  const int jb = blockIdx.x & 31;
  const int b0 = (blockIdx.x >> 5) * 32;
  const int t = threadIdx.x;
  const int w = t >> 6, lane = t & 63, l15 = lane & 15, quad = lane >> 4;
  const int mt = w & 1, nt = w >> 1;
  const int d = nt * 16 + l15;

  // prefetch ALL W fragments up front (latency hides under y staging)
  f16x8 wreg[8];
  {
    const f16x8* Wg8 = reinterpret_cast<const f16x8*>(Wy) + (size_t)jb * 2048;
    #pragma unroll
    for (int kt = 0; kt < 8; ++kt) wreg[kt] = Wg8[kt * 256 + d * 4 + quad];
  }
  f16x8 wt8r[8];
  if (!final_iter) {
    const f16x8* WT8 = reinterpret_cast<const f16x8*>(WTd) + (size_t)jb * 2048;
    #pragma unroll
    for (int qx = 0; qx < 4; ++qx) {
      const int cc = ((w >> 1) * 4 + qx) * 16 + l15;
      #pragma unroll
      for (int kt = 0; kt < 2; ++kt)
        wt8r[qx * 2 + kt] = WT8[kt * 1024 + cc * 4 + quad];
    }
  }

  #pragma unroll
  for (int p0 = 0; p0 < 2; ++p0) {
    const int p = p0 * 512 + t;
    const int bs = p >> 5, co = (p & 31) * 8;
    *reinterpret_cast<f16x8*>(&ysh[bs * 264 + co]) =
        *reinterpret_cast<const f16x8*>(
            &y16[(size_t)(b0 + bs) * 8192 + jb * 256 + co]);
  }
  if (t < 32) {
    csums[t] = csum_ws[(b0 + t) * 32 + jb];
    n2sh[t] = 0.f;
    vbsh[t] = 0.f;
  }
  __syncthreads();

  // ---- s-GEMM: wave w -> (mt, nt) ----
  f32x4 sacc = (f32x4){0.f, 0.f, 0.f, 0.f};
  #pragma unroll
  for (int kt = 0; kt < 8; ++kt) {
    const int ko = kt * 32 + quad * 8;
    f16x8 a = *reinterpret_cast<const f16x8*>(&ysh[(mt * 16 + l15) * 264 + ko]);
    sacc = __builtin_amdgcn_mfma_f32_16x16x32_f16(a, wreg[kt], sacc, 0, 0, 0);
  }
  const float biasd = bias[jb * 64 + d];
  float sv[4];
  #pragma unroll
  for (int rr = 0; rr < 4; ++rr)
    sv[rr] = sacc[rr] + biasd * csums[mt * 16 + quad * 4 + rr];

  #pragma unroll
  for (int rr = 0; rr < 4; ++rr) {
    float p = sv[rr] * sv[rr];
    p += __shfl_xor(p, 1);
    p += __shfl_xor(p, 2);
    p += __shfl_xor(p, 4);
    p += __shfl_xor(p, 8);
    if (l15 == 0) atomicAdd(&n2sh[mt * 16 + quad * 4 + rr], p);
  }
  __syncthreads();

  float vv[4];
  #pragma unroll
  for (int rr = 0; rr < 4; ++rr) {
    const float n2 = n2sh[mt * 16 + quad * 4 + rr];
    const float sc = sqrtf(n2) / (1.f + n2);
    vv[rr] = sv[rr] * sc;
  }

  if (final_iter) {
    #pragma unroll
    for (int rr = 0; rr < 4; ++rr)
      vout[((size_t)(b0 + mt * 16 + quad * 4 + rr) * 32 + jb) * 64 + d] = vv[rr];
  } else {
    #pragma unroll
    for (int rr = 0; rr < 4; ++rr) {
      vsh[(mt * 16 + quad * 4 + rr) * 72 + d] = (_Float16)vv[rr];
      float p = vv[rr] * biasd;
      p += __shfl_xor(p, 1);
      p += __shfl_xor(p, 2);
      p += __shfl_xor(p, 4);
      p += __shfl_xor(p, 8);
      if (l15 == 0) atomicAdd(&vbsh[mt * 16 + quad * 4 + rr], p);
    }
    __syncthreads();   // vsh/vbsh complete; ysh reads done -> reuse ysh
    if (t < 32) vb_ws[(b0 + t) * 32 + jb] = vbsh[t];

    // ---- u-GEMM: wave w -> (mt, ntu = (w>>1)*4 + qx), W in regs ----
    #pragma unroll
    for (int qx = 0; qx < 4; ++qx) {
      const int cc = ((w >> 1) * 4 + qx) * 16 + l15;
      f32x4 ua = (f32x4){0.f, 0.f, 0.f, 0.f};
      #pragma unroll
      for (int kt = 0; kt < 2; ++kt) {
        const int ko = kt * 32 + quad * 8;
        f16x8 a =
            *reinterpret_cast<const f16x8*>(&vsh[(mt * 16 + l15) * 72 + ko]);
        ua = __builtin_amdgcn_mfma_f32_16x16x32_f16(a, wt8r[qx * 2 + kt], ua, 0, 0, 0);
      }
      #pragma unroll
      for (int rr = 0; rr < 4; ++rr)
        ysh[(mt * 16 + quad * 4 + rr) * 264 + cc] = (_Float16)ua[rr];
    }
    __syncthreads();
    // coalesced u16 write-out
    #pragma unroll
    for (int p0 = 0; p0 < 2; ++p0) {
      const int p = p0 * 512 + t;
      const int bs = p >> 5, co = (p & 31) * 8;
      *reinterpret_cast<f16x8*>(&u16[(size_t)(b0 + bs) * 8192 + jb * 256 + co]) =
          *reinterpret_cast<const f16x8*>(&ysh[bs * 264 + co]);
    }
  }
}

// ---------------------------------------------------------------------------
extern "C" void kernel_launch(void* const* d_in, const int* in_sizes, int n_in,
                              void* d_out, int out_size, void* d_ws, size_t ws_size,
                              hipStream_t stream) {
  (void)in_sizes; (void)n_in; (void)out_size; (void)ws_size;
  const float* x      = (const float*)d_in[0];
  const float* W      = (const float*)d_in[1];
  const float* bias   = (const float*)d_in[2];
  const float* b_init = (const float*)d_in[3];
  char* ws = (char*)d_ws;

  _Float16* x16y = (_Float16*)(ws);                             // 32 MiB
  _Float16* xTd  = (_Float16*)(ws + (32u << 20));               // 32 MiB
  _Float16* y16  = (_Float16*)(ws + (64u << 20));               // 4 MiB
  _Float16* u16a = (_Float16*)(ws + (68u << 20));               // 4 MiB
  _Float16* u16b = (_Float16*)(ws + (72u << 20));               // 4 MiB
  float*    b2   = (float*)(ws + (76u << 20));                  // 8 MiB
  _Float16* Wy   = (_Float16*)(ws + (84u << 20));               // 1 MiB
  _Float16* WTd  = (_Float16*)(ws + (85u << 20));               // 1 MiB
  float*    csum = (float*)(ws + (86u << 20));                  // 32 KiB
  float*    vb0  = (float*)(ws + (86u << 20) + (32u << 10));    // 32 KiB
  float*    vb1  = (float*)(ws + (86u << 20) + (64u << 10));    // 32 KiB
  float*    vout = (float*)d_out;

  kXW<<<2080, 256, 0, stream>>>(x, W, x16y, xTd, Wy, WTd);
  // iter 1: softmax(b_init), y
  kR<<<256, 1024, 0, stream>>>(x16y, xTd, u16a, vb0, b_init, b2, y16, csum, 0);
  k2<<<256, 512, 0, stream>>>(Wy, WTd, bias, y16, csum, u16a, vb0, vout, 0);
  // iter 2: b = b_init + D(u0)+vb0, checkpoint b2
  kR<<<256, 1024, 0, stream>>>(x16y, xTd, u16a, vb0, b_init, b2, y16, csum, 1);
  k2<<<256, 512, 0, stream>>>(Wy, WTd, bias, y16, csum, u16b, vb1, vout, 0);
  // iter 3: b = b2 + D(u1)+vb1 (single delta pass)
  kR<<<256, 1024, 0, stream>>>(x16y, xTd, u16b, vb1, b2, b2, y16, csum, 2);
  k2<<<256, 512, 0, stream>>>(Wy, WTd, bias, y16, csum, u16a, vb0, vout, 1);
}

// Round 8
// 182.164 us; speedup vs baseline: 1.1148x; 1.0361x over previous
//
#include <hip/hip_runtime.h>

// CapsNet dynamic routing — 7 launches.
//   kXW: x-blocks (b = bid&255, p = bid>>8; XCD-matched so all 8 p-slices of
//        batch b land on XCD b%8, same as kR block b): load 32KB fp32 tile
//        ONCE (coalesced), convert -> XOR-swizzled LDS f16 tile, emit BOTH
//        frag layouts (x16y, xTd) with wave-contiguous 1KB stores.
//        Blocks 2048-2079: W fp32 -> Wy + WTd (no LDS).
//   kR:  grid 256 (block=batch), block 1024 (16 waves). No x staging:
//        u A-frags per-wave from global (L1 broadcast), x B-frags from frag
//        buffers into regs (dbf/ybf). y repacked via SB -> coalesced f16x8
//        stores. mode 0: softmax(b_init)+y. mode 1: delta=u0@xT,
//        b=b_init+D0+vb0, checkpoint b2 (fp32), y. mode 2: b=b2+D1+vb1, y.
//   k2:  grid 256 = (j, 32-batch chunk), block 512. Wy+WTd prefetched to
//        regs. s-GEMM + bias*csum, squash, u-GEMM -> u16 (+vb) or vout.

#define BSZ 256

typedef _Float16 f16x8 __attribute__((ext_vector_type(8)));
typedef float f32x4 __attribute__((ext_vector_type(4)));

// ---------------------------------------------------------------------------
// kXW: grid 2080, block 256.
// x16y f16x8 idx (per b, 8192): kk*1024 + c*4 + qd (kk=i>>5, qd=(i>>3)&3,
//   e=i&7)
// xTd  f16x8 idx (per b, 8192): kt*1024 + i*4 + qd (kt=c>>5, qd=(c>>3)&3,
//   e=c&7)
// LDS tile: 32 c-rows x 264 i, f16, byte_off = (row*264+col)*2 ^ ((row>>3)&3)<<5
//   (XOR spreads the 8-row strided xTd gather across bank quads; 16B-aligned
//   accesses preserved since XOR operates on byte bit 5 only.)
// ---------------------------------------------------------------------------
__global__ __launch_bounds__(256) void kXW(
    const float* __restrict__ x,        // [b][c][i] fp32
    const float* __restrict__ W,        // [32*64][256] fp32
    _Float16* __restrict__ x16y,
    _Float16* __restrict__ xTd,
    _Float16* __restrict__ Wy,
    _Float16* __restrict__ WTd)
{
  __shared__ __align__(16) _Float16 xls[32 * 264];   // 16.5 KiB
  const int t = threadIdx.x;

  if (blockIdx.x >= 2048) {
    // ---- W prep (no LDS): j = blockIdx.x - 2048 ----
    const int j = blockIdx.x - 2048;
    const float* Wj = W + (size_t)j * 64 * 256;
    {
      const int d = t & 63, quad = t >> 6;
      f16x8* out = reinterpret_cast<f16x8*>(Wy) + (size_t)j * 2048;
      #pragma unroll
      for (int kt = 0; kt < 8; ++kt) {
        const int c0 = kt * 32 + quad * 8;
        f32x4 v0 = *reinterpret_cast<const f32x4*>(&Wj[d * 256 + c0]);
        f32x4 v1 = *reinterpret_cast<const f32x4*>(&Wj[d * 256 + c0 + 4]);
        f16x8 hv;
        #pragma unroll
        for (int e = 0; e < 4; ++e) {
          hv[e] = (_Float16)v0[e];
          hv[4 + e] = (_Float16)v1[e];
        }
        out[kt * 256 + d * 4 + quad] = hv;
      }
    }
    {
      const int cc = t;
      f16x8* out = reinterpret_cast<f16x8*>(WTd) + (size_t)j * 2048;
      #pragma unroll
      for (int h8 = 0; h8 < 8; ++h8) {
        const int kt = h8 >> 2, quad = h8 & 3;
        f16x8 hv;
        #pragma unroll
        for (int e = 0; e < 8; ++e)
          hv[e] = (_Float16)Wj[(h8 * 8 + e) * 256 + cc];   // column, L2-hot
        out[kt * 1024 + cc * 4 + quad] = hv;
      }
    }
    return;
  }

  // ---- x conversion: b = bid&255, p = bid>>8 (XCD-matched) ----
  const int b = blockIdx.x & 255, p = blockIdx.x >> 8;
  const float* xb = x + (size_t)b * 65536 + (size_t)p * 32 * 256;
  char* lbase = reinterpret_cast<char*>(xls);

  // load fp32 tile (coalesced 1KB/wave) -> convert -> swizzled LDS
  #pragma unroll
  for (int rep = 0; rep < 4; ++rep) {
    const int idx8 = rep * 256 + t;          // 8-float group id
    const int row = idx8 >> 5, col8 = (idx8 & 31) * 8;
    f32x4 v0 = *reinterpret_cast<const f32x4*>(&xb[row * 256 + col8]);
    f32x4 v1 = *reinterpret_cast<const f32x4*>(&xb[row * 256 + col8 + 4]);
    f16x8 hv;
    #pragma unroll
    for (int e = 0; e < 4; ++e) {
      hv[e] = (_Float16)v0[e];
      hv[4 + e] = (_Float16)v1[e];
    }
    const int boff = ((row * 264 + col8) * 2) ^ (((row >> 3) & 3) << 5);
    *reinterpret_cast<f16x8*>(lbase + boff) = hv;
  }
  __syncthreads();

  const int w = t >> 6, l = t & 63;

  // pass A: x16y — wave-store = 64 consecutive vecs (1KB contiguous)
  {
    f16x8* xy8 = reinterpret_cast<f16x8*>(x16y) + (size_t)b * 8192;
    #pragma unroll
    for (int rep = 0; rep < 4; ++rep) {
      const int tk = rep * 4 + w;            // 0..15
      const int kk = tk >> 1, half = tk & 1;
      const int cl = half * 16 + (l >> 2), qd = l & 3;
      const int i8 = kk * 32 + qd * 8;
      const int boff = ((cl * 264 + i8) * 2) ^ (((cl >> 3) & 3) << 5);
      f16x8 hv = *reinterpret_cast<const f16x8*>(lbase + boff);
      xy8[kk * 1024 + p * 128 + half * 64 + l] = hv;   // base + lane
    }
  }

  // pass B: xTd — per-lane 8-row gather (conflict-free via XOR), 1KB stores
  {
    f16x8* xt8 = reinterpret_cast<f16x8*>(xTd) + (size_t)b * 8192;
    #pragma unroll
    for (int rep = 0; rep < 4; ++rep) {
      const int tk = rep * 4 + w;            // 0..15
      const int ig = tk * 16 + (l >> 2), qd = l & 3;
      f16x8 hv;
      #pragma unroll
      for (int e = 0; e < 8; ++e) {
        const int row = qd * 8 + e;
        const int boff = ((row * 264 + ig) * 2) ^ (((row >> 3) & 3) << 5);
        hv[e] = *reinterpret_cast<const _Float16*>(lbase + boff);
      }
      xt8[p * 1024 + tk * 64 + l] = hv;      // base + lane
    }
  }
}

// ---------------------------------------------------------------------------
// kR: grid 256 (block=batch), block 1024 (16 waves). Wave w owns columns
// ii = w*16 + l15 (i for routing, c for the y-GEMM).
// delta B-frag: xTd vec[kt*1024 + ii*4 + quad]  -> dbf regs
// y     B-frag: x16y vec[kk*1024 + ii*4 + quad] -> ybf regs
// u A-frags read per-wave direct from global (identical across waves -> L1)
// y repacked D-layout -> SB -> coalesced f16x8 stores.
// ---------------------------------------------------------------------------
__global__ __launch_bounds__(1024) void kR(
    const _Float16* __restrict__ x16y,
    const _Float16* __restrict__ xTd,
    const _Float16* __restrict__ u,     // [b][j][c]  (modes 1,2)
    const float* __restrict__ vb,       // [b][j]     (modes 1,2)
    const float* __restrict__ bsrc,     // [b][j][i]  (b_init or b2)
    float* __restrict__ b2out,          // [b][j][i]  (mode 1 writes)
    _Float16* __restrict__ y16,         // [b][j][c]
    float* __restrict__ csum_ws,        // [b][j]
    int mode)
{
  __shared__ __align__(16) _Float16 cs[32 * 264];  // softmax out
  __shared__ __align__(16) _Float16 SB[32 * 264];  // y repack stage
  __shared__ float csumsh[32];

  const int b = blockIdx.x, t = threadIdx.x;
  const int w = t >> 6, lane = t & 63, l15 = lane & 15, quad = lane >> 4;
  const int ii = w * 16 + l15;
  const float* bp = bsrc + (size_t)b * 8192;
  const f16x8* xy8 = reinterpret_cast<const f16x8*>(x16y) + (size_t)b * 8192;

  if (t < 32) csumsh[t] = 0.f;
  __syncthreads();  // B0: trivial (no memory waits before it)

  // routing logits (coalesced)
  float breg[2][4];
  #pragma unroll
  for (int mt = 0; mt < 2; ++mt)
    #pragma unroll
    for (int rr = 0; rr < 4; ++rr)
      breg[mt][rr] = bp[(mt * 16 + quad * 4 + rr) * 256 + ii];

  f16x8 ybf[8];
  if (mode != 0) {
    // prefetch delta B-frags to regs
    f16x8 dbf[8];
    {
      const f16x8* xt8 = reinterpret_cast<const f16x8*>(xTd) + (size_t)b * 8192;
      #pragma unroll
      for (int kt = 0; kt < 8; ++kt)
        dbf[kt] = xt8[kt * 1024 + ii * 4 + quad];
    }
    // ---- delta-GEMM: D[j, ii] = sum_c u[j,c] x[c,ii] ----
    // A-frags direct from global u (16KB/batch, L1-broadcast across waves)
    const _Float16* ug = u + (size_t)b * 8192;
    f32x4 acc0 = (f32x4){0.f, 0.f, 0.f, 0.f};
    f32x4 acc1 = (f32x4){0.f, 0.f, 0.f, 0.f};
    #pragma unroll
    for (int kt = 0; kt < 8; ++kt) {
      const int ko = kt * 32 + quad * 8;
      f16x8 a0 = *reinterpret_cast<const f16x8*>(&ug[l15 * 256 + ko]);
      f16x8 a1 = *reinterpret_cast<const f16x8*>(&ug[(16 + l15) * 256 + ko]);
      acc0 = __builtin_amdgcn_mfma_f32_16x16x32_f16(a0, dbf[kt], acc0, 0, 0, 0);
      acc1 = __builtin_amdgcn_mfma_f32_16x16x32_f16(a1, dbf[kt], acc1, 0, 0, 0);
    }
    #pragma unroll
    for (int rr = 0; rr < 4; ++rr) {
      const int j0 = quad * 4 + rr;
      breg[0][rr] += acc0[rr] + vb[b * 32 + j0];        // broadcast loads
      breg[1][rr] += acc1[rr] + vb[b * 32 + 16 + j0];
    }
    // prefetch y B-frags; latency hides under b2 store + softmax VALU
    #pragma unroll
    for (int kk = 0; kk < 8; ++kk)
      ybf[kk] = xy8[kk * 1024 + ii * 4 + quad];
    if (mode == 1) {
      // checkpoint b2 = b_init + D0 + vb0 (fp32, bit-identical to recompute)
      float* bo = b2out + (size_t)b * 8192;
      #pragma unroll
      for (int mt = 0; mt < 2; ++mt)
        #pragma unroll
        for (int rr = 0; rr < 4; ++rr)
          bo[(mt * 16 + quad * 4 + rr) * 256 + ii] = breg[mt][rr];
    }
  } else {
    #pragma unroll
    for (int kk = 0; kk < 8; ++kk)
      ybf[kk] = xy8[kk * 1024 + ii * 4 + quad];
  }

  // ---- softmax over j (registers + shfl across quads/halves) ----
  float cf[2][4];
  {
    float m = breg[0][0];
    #pragma unroll
    for (int mt = 0; mt < 2; ++mt)
      #pragma unroll
      for (int rr = 0; rr < 4; ++rr) m = fmaxf(m, breg[mt][rr]);
    m = fmaxf(m, __shfl_xor(m, 16));
    m = fmaxf(m, __shfl_xor(m, 32));
    float s = 0.f;
    #pragma unroll
    for (int mt = 0; mt < 2; ++mt)
      #pragma unroll
      for (int rr = 0; rr < 4; ++rr) {
        float e = __expf(breg[mt][rr] - m);
        cf[mt][rr] = e; s += e;
      }
    s += __shfl_xor(s, 16);
    s += __shfl_xor(s, 32);
    const float rinv = 1.f / s;
    #pragma unroll
    for (int mt = 0; mt < 2; ++mt)
      #pragma unroll
      for (int rr = 0; rr < 4; ++rr) {
        const float cv = cf[mt][rr] * rinv;
        cf[mt][rr] = cv;
        cs[(mt * 16 + quad * 4 + rr) * 264 + ii] = (_Float16)cv;
      }
  }

  // csum[j] (atomics BEFORE the barrier; init done at B0)
  #pragma unroll
  for (int mt = 0; mt < 2; ++mt)
    #pragma unroll
    for (int rr = 0; rr < 4; ++rr) {
      float pj = cf[mt][rr];
      pj += __shfl_xor(pj, 1);
      pj += __shfl_xor(pj, 2);
      pj += __shfl_xor(pj, 4);
      pj += __shfl_xor(pj, 8);
      if (l15 == 0) atomicAdd(&csumsh[mt * 16 + quad * 4 + rr], pj);
    }

  __syncthreads();  // B2: cs + csum atomics visible

  // ---- y[j,c] = sum_i c[j,i] x[c,i]; wave w covers c = ii (B in regs) ----
  {
    f32x4 acy0 = (f32x4){0.f, 0.f, 0.f, 0.f};
    f32x4 acy1 = (f32x4){0.f, 0.f, 0.f, 0.f};
    #pragma unroll
    for (int kk = 0; kk < 8; ++kk) {
      const int ko = kk * 32 + quad * 8;
      f16x8 a0 = *reinterpret_cast<const f16x8*>(&cs[l15 * 264 + ko]);
      f16x8 a1 = *reinterpret_cast<const f16x8*>(&cs[(16 + l15) * 264 + ko]);
      acy0 = __builtin_amdgcn_mfma_f32_16x16x32_f16(a0, ybf[kk], acy0, 0, 0, 0);
      acy1 = __builtin_amdgcn_mfma_f32_16x16x32_f16(a1, ybf[kk], acy1, 0, 0, 0);
    }
    // repack D-layout -> SB (SB unused until here; no barrier needed)
    #pragma unroll
    for (int rr = 0; rr < 4; ++rr) {
      SB[(quad * 4 + rr) * 264 + ii] = (_Float16)acy0[rr];
      SB[(16 + quad * 4 + rr) * 264 + ii] = (_Float16)acy1[rr];
    }
  }
  __syncthreads();  // B3: repack complete

  *reinterpret_cast<f16x8*>(
      &y16[(size_t)b * 8192 + (t >> 5) * 256 + (t & 31) * 8]) =
      *reinterpret_cast<const f16x8*>(&SB[(t >> 5) * 264 + (t & 31) * 8]);
  if (t < 32) csum_ws[b * 32 + t] = csumsh[t];
}

// ---------------------------------------------------------------------------
// k2: grid 256 = 32 j x 8 chunks of 32 batches, block 512 (8 waves).
// ---------------------------------------------------------------------------
__global__ __launch_bounds__(512) void k2(
    const _Float16* __restrict__ Wy,
    const _Float16* __restrict__ WTd,
    const float* __restrict__ bias,
    const _Float16* __restrict__ y16,   // [b][j][c]
    const float* __restrict__ csum_ws,  // [b][j]
    _Float16* __restrict__ u16,         // [b][j][c] (target buffer)
    float* __restrict__ vb_ws,          // [b][j]
    float* __restrict__ vout,           // [b][j][d]
    int final_iter)
{
  __shared__ __align__(16) _Float16 ysh[32 * 264];   // y stage, then u-repack
  __shared__ __align__(16) _Float16 vsh[32 * 72];
  __shared__ float n2sh[32];
  __shared__ float vbsh[32];
  __shared__ float csums[32];

  const int jb = blockIdx.x & 31;
  const int b0 = (blockIdx.x >> 5) * 32;
  const int t = threadIdx.x;
  const int w = t >> 6, lane = t & 63, l15 = lane & 15, quad = lane >> 4;
  const int mt = w & 1, nt = w >> 1;
  const int d = nt * 16 + l15;

  // prefetch ALL W fragments up front (latency hides under y staging)
  f16x8 wreg[8];
  {
    const f16x8* Wg8 = reinterpret_cast<const f16x8*>(Wy) + (size_t)jb * 2048;
    #pragma unroll
    for (int kt = 0; kt < 8; ++kt) wreg[kt] = Wg8[kt * 256 + d * 4 + quad];
  }
  f16x8 wt8r[8];
  if (!final_iter) {
    const f16x8* WT8 = reinterpret_cast<const f16x8*>(WTd) + (size_t)jb * 2048;
    #pragma unroll
    for (int qx = 0; qx < 4; ++qx) {
      const int cc = ((w >> 1) * 4 + qx) * 16 + l15;
      #pragma unroll
      for (int kt = 0; kt < 2; ++kt)
        wt8r[qx * 2 + kt] = WT8[kt * 1024 + cc * 4 + quad];
    }
  }

  #pragma unroll
  for (int p0 = 0; p0 < 2; ++p0) {
    const int p = p0 * 512 + t;
    const int bs = p >> 5, co = (p & 31) * 8;
    *reinterpret_cast<f16x8*>(&ysh[bs * 264 + co]) =
        *reinterpret_cast<const f16x8*>(
            &y16[(size_t)(b0 + bs) * 8192 + jb * 256 + co]);
  }
  if (t < 32) {
    csums[t] = csum_ws[(b0 + t) * 32 + jb];
    n2sh[t] = 0.f;
    vbsh[t] = 0.f;
  }
  __syncthreads();

  // ---- s-GEMM: wave w -> (mt, nt) ----
  f32x4 sacc = (f32x4){0.f, 0.f, 0.f, 0.f};
  #pragma unroll
  for (int kt = 0; kt < 8; ++kt) {
    const int ko = kt * 32 + quad * 8;
    f16x8 a = *reinterpret_cast<const f16x8*>(&ysh[(mt * 16 + l15) * 264 + ko]);
    sacc = __builtin_amdgcn_mfma_f32_16x16x32_f16(a, wreg[kt], sacc, 0, 0, 0);
  }
  const float biasd = bias[jb * 64 + d];
  float sv[4];
  #pragma unroll
  for (int rr = 0; rr < 4; ++rr)
    sv[rr] = sacc[rr] + biasd * csums[mt * 16 + quad * 4 + rr];

  #pragma unroll
  for (int rr = 0; rr < 4; ++rr) {
    float p = sv[rr] * sv[rr];
    p += __shfl_xor(p, 1);
    p += __shfl_xor(p, 2);
    p += __shfl_xor(p, 4);
    p += __shfl_xor(p, 8);
    if (l15 == 0) atomicAdd(&n2sh[mt * 16 + quad * 4 + rr], p);
  }
  __syncthreads();

  float vv[4];
  #pragma unroll
  for (int rr = 0; rr < 4; ++rr) {
    const float n2 = n2sh[mt * 16 + quad * 4 + rr];
    const float sc = sqrtf(n2) / (1.f + n2);
    vv[rr] = sv[rr] * sc;
  }

  if (final_iter) {
    #pragma unroll
    for (int rr = 0; rr < 4; ++rr)
      vout[((size_t)(b0 + mt * 16 + quad * 4 + rr) * 32 + jb) * 64 + d] = vv[rr];
  } else {
    #pragma unroll
    for (int rr = 0; rr < 4; ++rr) {
      vsh[(mt * 16 + quad * 4 + rr) * 72 + d] = (_Float16)vv[rr];
      float p = vv[rr] * biasd;
      p += __shfl_xor(p, 1);
      p += __shfl_xor(p, 2);
      p += __shfl_xor(p, 4);
      p += __shfl_xor(p, 8);
      if (l15 == 0) atomicAdd(&vbsh[mt * 16 + quad * 4 + rr], p);
    }
    __syncthreads();   // vsh/vbsh complete; ysh reads done -> reuse ysh
    if (t < 32) vb_ws[(b0 + t) * 32 + jb] = vbsh[t];

    // ---- u-GEMM: wave w -> (mt, ntu = (w>>1)*4 + qx), W in regs ----
    #pragma unroll
    for (int qx = 0; qx < 4; ++qx) {
      const int cc = ((w >> 1) * 4 + qx) * 16 + l15;
      f32x4 ua = (f32x4){0.f, 0.f, 0.f, 0.f};
      #pragma unroll
      for (int kt = 0; kt < 2; ++kt) {
        const int ko = kt * 32 + quad * 8;
        f16x8 a =
            *reinterpret_cast<const f16x8*>(&vsh[(mt * 16 + l15) * 72 + ko]);
        ua = __builtin_amdgcn_mfma_f32_16x16x32_f16(a, wt8r[qx * 2 + kt], ua, 0, 0, 0);
      }
      #pragma unroll
      for (int rr = 0; rr < 4; ++rr)
        ysh[(mt * 16 + quad * 4 + rr) * 264 + cc] = (_Float16)ua[rr];
    }
    __syncthreads();
    // coalesced u16 write-out
    #pragma unroll
    for (int p0 = 0; p0 < 2; ++p0) {
      const int p = p0 * 512 + t;
      const int bs = p >> 5, co = (p & 31) * 8;
      *reinterpret_cast<f16x8*>(&u16[(size_t)(b0 + bs) * 8192 + jb * 256 + co]) =
          *reinterpret_cast<const f16x8*>(&ysh[bs * 264 + co]);
    }
  }
}

// ---------------------------------------------------------------------------
extern "C" void kernel_launch(void* const* d_in, const int* in_sizes, int n_in,
                              void* d_out, int out_size, void* d_ws, size_t ws_size,
                              hipStream_t stream) {
  (void)in_sizes; (void)n_in; (void)out_size; (void)ws_size;
  const float* x      = (const float*)d_in[0];
  const float* W      = (const float*)d_in[1];
  const float* bias   = (const float*)d_in[2];
  const float* b_init = (const float*)d_in[3];
  char* ws = (char*)d_ws;

  _Float16* x16y = (_Float16*)(ws);                             // 32 MiB
  _Float16* xTd  = (_Float16*)(ws + (32u << 20));               // 32 MiB
  _Float16* y16  = (_Float16*)(ws + (64u << 20));               // 4 MiB
  _Float16* u16a = (_Float16*)(ws + (68u << 20));               // 4 MiB
  _Float16* u16b = (_Float16*)(ws + (72u << 20));               // 4 MiB
  float*    b2   = (float*)(ws + (76u << 20));                  // 8 MiB
  _Float16* Wy   = (_Float16*)(ws + (84u << 20));               // 1 MiB
  _Float16* WTd  = (_Float16*)(ws + (85u << 20));               // 1 MiB
  float*    csum = (float*)(ws + (86u << 20));                  // 32 KiB
  float*    vb0  = (float*)(ws + (86u << 20) + (32u << 10));    // 32 KiB
  float*    vb1  = (float*)(ws + (86u << 20) + (64u << 10));    // 32 KiB
  float*    vout = (float*)d_out;

  kXW<<<2080, 256, 0, stream>>>(x, W, x16y, xTd, Wy, WTd);
  // iter 1: softmax(b_init), y
  kR<<<256, 1024, 0, stream>>>(x16y, xTd, u16a, vb0, b_init, b2, y16, csum, 0);
  k2<<<256, 512, 0, stream>>>(Wy, WTd, bias, y16, csum, u16a, vb0, vout, 0);
  // iter 2: b = b_init + D(u0)+vb0, checkpoint b2
  kR<<<256, 1024, 0, stream>>>(x16y, xTd, u16a, vb0, b_init, b2, y16, csum, 1);
  k2<<<256, 512, 0, stream>>>(Wy, WTd, bias, y16, csum, u16b, vb1, vout, 0);
  // iter 3: b = b2 + D(u1)+vb1 (single delta pass)
  kR<<<256, 1024, 0, stream>>>(x16y, xTd, u16b, vb1, b2, b2, y16, csum, 2);
  k2<<<256, 512, 0, stream>>>(Wy, WTd, bias, y16, csum, u16a, vb0, vout, 1);
}

// Round 9
// 179.923 us; speedup vs baseline: 1.1287x; 1.0125x over previous
//
#include <hip/hip_runtime.h>

// CapsNet dynamic routing — 7 launches, single x layout (x16y), no xTd.
//   kXW: blocks 0-2047 (b = bid&255, p = bid>>8, XCD-matched): convert x
//        rows [p*32,p*32+32) fp32 -> x16y frags. No LDS: reads are 128B
//        contiguous segments, writes wave-contiguous 1KB. Blocks 2048+: W.
//   kR:  grid 256 (block=batch), block 1024 (16 waves).
//        mode 0: softmax(b_init) + y (ybf direct from global).
//        modes 1/2: fill xs LDS (128KB, x16y-linear) via global_load_lds;
//        delta B-frags via strided u16 LDS reads (R1-verified formula);
//        u A-frags per-wave from global (L1 broadcast); y B-frags from LDS.
//        b = b_init + D0 + vb0 (mode 1, checkpoints b2 fp32) or
//        b = b2 + D1 + vb1 (mode 2). y repack aliases cs after barrier.
//   k2:  grid 256 = (j, 32-batch chunk), block 512. Wy+WTd prefetched to
//        regs. s-GEMM + bias*csum, squash, u-GEMM -> u16 (+vb) or vout.

#define BSZ 256

typedef _Float16 f16x8 __attribute__((ext_vector_type(8)));
typedef float f32x4 __attribute__((ext_vector_type(4)));

__device__ __forceinline__ void gload_lds16(const void* g, void* l) {
  __builtin_amdgcn_global_load_lds(
      (const __attribute__((address_space(1))) void*)g,
      (__attribute__((address_space(3))) void*)l, 16, 0, 0);
}

// ---------------------------------------------------------------------------
// kXW: grid 2080, block 256. No LDS.
// x16y f16x8 idx (per b, 8192): kk*1024 + c*4 + qd (kk=i>>5, qd=(i>>3)&3,
//   e=i&7)
// Wy  f16x8 idx (per j, 2048): kt*256 + d*4 + quad   (kt=c>>5, e=c&7)
// WTd f16x8 idx (per j, 2048): kt*1024 + cc*4 + quad (kt=d>>5, e=d&7)
// ---------------------------------------------------------------------------
__global__ __launch_bounds__(256) void kXW(
    const float* __restrict__ x,        // [b][c][i] fp32
    const float* __restrict__ W,        // [32*64][256] fp32
    _Float16* __restrict__ x16y,
    _Float16* __restrict__ Wy,
    _Float16* __restrict__ WTd)
{
  const int t = threadIdx.x;

  if (blockIdx.x >= 2048) {
    // ---- W prep (no LDS): j = blockIdx.x - 2048 ----
    const int j = blockIdx.x - 2048;
    const float* Wj = W + (size_t)j * 64 * 256;
    {
      const int d = t & 63, quad = t >> 6;
      f16x8* out = reinterpret_cast<f16x8*>(Wy) + (size_t)j * 2048;
      #pragma unroll
      for (int kt = 0; kt < 8; ++kt) {
        const int c0 = kt * 32 + quad * 8;
        f32x4 v0 = *reinterpret_cast<const f32x4*>(&Wj[d * 256 + c0]);
        f32x4 v1 = *reinterpret_cast<const f32x4*>(&Wj[d * 256 + c0 + 4]);
        f16x8 hv;
        #pragma unroll
        for (int e = 0; e < 4; ++e) {
          hv[e] = (_Float16)v0[e];
          hv[4 + e] = (_Float16)v1[e];
        }
        out[kt * 256 + d * 4 + quad] = hv;
      }
    }
    {
      const int cc = t;
      f16x8* out = reinterpret_cast<f16x8*>(WTd) + (size_t)j * 2048;
      #pragma unroll
      for (int h8 = 0; h8 < 8; ++h8) {
        const int kt = h8 >> 2, quad = h8 & 3;
        f16x8 hv;
        #pragma unroll
        for (int e = 0; e < 8; ++e)
          hv[e] = (_Float16)Wj[(h8 * 8 + e) * 256 + cc];   // column, L2-hot
        out[kt * 1024 + cc * 4 + quad] = hv;
      }
    }
    return;
  }

  // ---- x conversion: b = bid&255, p = bid>>8 (XCD-matched to kR block b) --
  const int b = blockIdx.x & 255, p = blockIdx.x >> 8;
  const float* xb = x + (size_t)b * 65536;
  f16x8* xy8 = reinterpret_cast<f16x8*>(x16y) + (size_t)b * 8192;
  const int w = t >> 6, l = t & 63;

  #pragma unroll
  for (int step = 0; step < 4; ++step) {
    const int tk = step * 4 + w;             // 0..15
    const int kk = tk >> 1, half = tk & 1;
    const int c = p * 32 + half * 16 + (l >> 2);
    const int qd = l & 3;
    const int i8 = kk * 32 + qd * 8;
    // reads: lanes qd=0..3 cover 128B contiguous at row c (full lines)
    f32x4 v0 = *reinterpret_cast<const f32x4*>(&xb[c * 256 + i8]);
    f32x4 v1 = *reinterpret_cast<const f32x4*>(&xb[c * 256 + i8 + 4]);
    f16x8 hv;
    #pragma unroll
    for (int e = 0; e < 4; ++e) {
      hv[e] = (_Float16)v0[e];
      hv[4 + e] = (_Float16)v1[e];
    }
    // write: vec = kk*1024 + p*128 + half*64 + l  (base + lane, 1KB/wave)
    xy8[kk * 1024 + c * 4 + qd] = hv;
  }
}

// ---------------------------------------------------------------------------
// kR: grid 256 (block=batch), block 1024 (16 waves). Wave w owns columns
// ii = w*16 + l15 (i for routing, c for the y-GEMM).
// xs (LDS, modes 1/2) mirrors x16y layout: element (c,i) at f16 offset
//   (i>>5)*8192 + c*32 + ((i>>3)&3)*8 + (i&7)
// delta B-frag: xs[xbase + (ko+e)*32] strided u16 (4-way conflict, accepted)
// y     B-frag: xs vec b128 (modes 1/2) or global x16y (mode 0)
// u A-frags per-wave direct from global (identical across waves -> L1)
// ---------------------------------------------------------------------------
__global__ __launch_bounds__(1024) void kR(
    const _Float16* __restrict__ x16y,
    const _Float16* __restrict__ u,     // [b][j][c]  (modes 1,2)
    const float* __restrict__ vb,       // [b][j]     (modes 1,2)
    const float* __restrict__ bsrc,     // [b][j][i]  (b_init or b2)
    float* __restrict__ b2out,          // [b][j][i]  (mode 1 writes)
    _Float16* __restrict__ y16,         // [b][j][c]
    float* __restrict__ csum_ws,        // [b][j]
    int mode)
{
  __shared__ __align__(16) _Float16 xs[65536];     // 128 KiB (modes 1/2)
  __shared__ __align__(16) _Float16 cs[32 * 264];  // softmax out -> y repack
  __shared__ float csumsh[32];

  const int b = blockIdx.x, t = threadIdx.x;
  const int w = t >> 6, lane = t & 63, l15 = lane & 15, quad = lane >> 4;
  const int ii = w * 16 + l15;
  const float* bp = bsrc + (size_t)b * 8192;
  const f16x8* xy8 = reinterpret_cast<const f16x8*>(x16y) + (size_t)b * 8192;

  if (t < 32) csumsh[t] = 0.f;

  f16x8 ybf[8];
  if (mode != 0) {
    // ---- async fill xs from x16y (linear dest: lane order == layout) ----
    #pragma unroll
    for (int it8 = 0; it8 < 8; ++it8) {
      const int vi = it8 * 1024 + t;
      gload_lds16(xy8 + vi, &xs[vi * 8]);
    }
  } else {
    // mode 0: y B-frags direct from global (issue early, hide under softmax)
    #pragma unroll
    for (int kk = 0; kk < 8; ++kk)
      ybf[kk] = xy8[kk * 1024 + ii * 4 + quad];
  }

  // routing logits (coalesced; overlap staging)
  float breg[2][4];
  #pragma unroll
  for (int mt = 0; mt < 2; ++mt)
    #pragma unroll
    for (int rr = 0; rr < 4; ++rr)
      breg[mt][rr] = bp[(mt * 16 + quad * 4 + rr) * 256 + ii];

  __syncthreads();  // B1: xs staged (vmcnt drained) / csumsh zeroed

  if (mode != 0) {
    // ---- delta-GEMM: D[j, ii] = sum_c u[j,c] x[c,ii] ----
    // A-frags from global u (16KB/batch, L1 broadcast); B from xs strided.
    const _Float16* ug = u + (size_t)b * 8192;
    const int xbase = ((ii >> 5) * 1024 + ((ii >> 3) & 3)) * 8 + (ii & 7);
    f32x4 acc0 = (f32x4){0.f, 0.f, 0.f, 0.f};
    f32x4 acc1 = (f32x4){0.f, 0.f, 0.f, 0.f};
    #pragma unroll
    for (int kt = 0; kt < 8; ++kt) {
      const int ko = kt * 32 + quad * 8;
      f16x8 bf;
      #pragma unroll
      for (int e = 0; e < 8; ++e)
        bf[e] = xs[xbase + (ko + e) * 32];   // x^T frag (R1-verified)
      f16x8 a0 = *reinterpret_cast<const f16x8*>(&ug[l15 * 256 + ko]);
      f16x8 a1 = *reinterpret_cast<const f16x8*>(&ug[(16 + l15) * 256 + ko]);
      acc0 = __builtin_amdgcn_mfma_f32_16x16x32_f16(a0, bf, acc0, 0, 0, 0);
      acc1 = __builtin_amdgcn_mfma_f32_16x16x32_f16(a1, bf, acc1, 0, 0, 0);
    }
    #pragma unroll
    for (int rr = 0; rr < 4; ++rr) {
      const int j0 = quad * 4 + rr;
      breg[0][rr] += acc0[rr] + vb[b * 32 + j0];        // broadcast loads
      breg[1][rr] += acc1[rr] + vb[b * 32 + 16 + j0];
    }
    if (mode == 1) {
      // checkpoint b2 = b_init + D0 + vb0 (fp32, bit-identical to recompute)
      float* bo = b2out + (size_t)b * 8192;
      #pragma unroll
      for (int mt = 0; mt < 2; ++mt)
        #pragma unroll
        for (int rr = 0; rr < 4; ++rr)
          bo[(mt * 16 + quad * 4 + rr) * 256 + ii] = breg[mt][rr];
    }
  }

  // ---- softmax over j (registers + shfl across quads/halves) ----
  float cf[2][4];
  {
    float m = breg[0][0];
    #pragma unroll
    for (int mt = 0; mt < 2; ++mt)
      #pragma unroll
      for (int rr = 0; rr < 4; ++rr) m = fmaxf(m, breg[mt][rr]);
    m = fmaxf(m, __shfl_xor(m, 16));
    m = fmaxf(m, __shfl_xor(m, 32));
    float s = 0.f;
    #pragma unroll
    for (int mt = 0; mt < 2; ++mt)
      #pragma unroll
      for (int rr = 0; rr < 4; ++rr) {
        float e = __expf(breg[mt][rr] - m);
        cf[mt][rr] = e; s += e;
      }
    s += __shfl_xor(s, 16);
    s += __shfl_xor(s, 32);
    const float rinv = 1.f / s;
    #pragma unroll
    for (int mt = 0; mt < 2; ++mt)
      #pragma unroll
      for (int rr = 0; rr < 4; ++rr) {
        const float cv = cf[mt][rr] * rinv;
        cf[mt][rr] = cv;
        cs[(mt * 16 + quad * 4 + rr) * 264 + ii] = (_Float16)cv;
      }
  }

  // y B-frags from xs (modes 1/2): xs stable since B1; overlaps csum shfl
  if (mode != 0) {
    #pragma unroll
    for (int kk = 0; kk < 8; ++kk)
      ybf[kk] = *reinterpret_cast<const f16x8*>(
          &xs[(kk * 1024 + ii * 4 + quad) * 8]);
  }

  // csum[j] (atomics BEFORE the barrier)
  #pragma unroll
  for (int mt = 0; mt < 2; ++mt)
    #pragma unroll
    for (int rr = 0; rr < 4; ++rr) {
      float pj = cf[mt][rr];
      pj += __shfl_xor(pj, 1);
      pj += __shfl_xor(pj, 2);
      pj += __shfl_xor(pj, 4);
      pj += __shfl_xor(pj, 8);
      if (l15 == 0) atomicAdd(&csumsh[mt * 16 + quad * 4 + rr], pj);
    }

  __syncthreads();  // B2: cs + csum atomics visible

  // ---- y[j,c] = sum_i c[j,i] x[c,i]; wave w covers c = ii (B in regs) ----
  f32x4 acy0 = (f32x4){0.f, 0.f, 0.f, 0.f};
  f32x4 acy1 = (f32x4){0.f, 0.f, 0.f, 0.f};
  #pragma unroll
  for (int kk = 0; kk < 8; ++kk) {
    const int ko = kk * 32 + quad * 8;
    f16x8 a0 = *reinterpret_cast<const f16x8*>(&cs[l15 * 264 + ko]);
    f16x8 a1 = *reinterpret_cast<const f16x8*>(&cs[(16 + l15) * 264 + ko]);
    acy0 = __builtin_amdgcn_mfma_f32_16x16x32_f16(a0, ybf[kk], acy0, 0, 0, 0);
    acy1 = __builtin_amdgcn_mfma_f32_16x16x32_f16(a1, ybf[kk], acy1, 0, 0, 0);
  }
  __syncthreads();  // B3: all cs reads done -> cs reusable as y-repack stage

  #pragma unroll
  for (int rr = 0; rr < 4; ++rr) {
    cs[(quad * 4 + rr) * 264 + ii] = (_Float16)acy0[rr];
    cs[(16 + quad * 4 + rr) * 264 + ii] = (_Float16)acy1[rr];
  }
  __syncthreads();  // B4: repack complete

  *reinterpret_cast<f16x8*>(
      &y16[(size_t)b * 8192 + (t >> 5) * 256 + (t & 31) * 8]) =
      *reinterpret_cast<const f16x8*>(&cs[(t >> 5) * 264 + (t & 31) * 8]);
  if (t < 32) csum_ws[b * 32 + t] = csumsh[t];
}

// ---------------------------------------------------------------------------
// k2: grid 256 = 32 j x 8 chunks of 32 batches, block 512 (8 waves).
// ---------------------------------------------------------------------------
__global__ __launch_bounds__(512) void k2(
    const _Float16* __restrict__ Wy,
    const _Float16* __restrict__ WTd,
    const float* __restrict__ bias,
    const _Float16* __restrict__ y16,   // [b][j][c]
    const float* __restrict__ csum_ws,  // [b][j]
    _Float16* __restrict__ u16,         // [b][j][c] (target buffer)
    float* __restrict__ vb_ws,          // [b][j]
    float* __restrict__ vout,           // [b][j][d]
    int final_iter)
{
  __shared__ __align__(16) _Float16 ysh[32 * 264];   // y stage, then u-repack
  __shared__ __align__(16) _Float16 vsh[32 * 72];
  __shared__ float n2sh[32];
  __shared__ float vbsh[32];
  __shared__ float csums[32];

  const int jb = blockIdx.x & 31;
  const int b0 = (blockIdx.x >> 5) * 32;
  const int t = threadIdx.x;
  const int w = t >> 6, lane = t & 63, l15 = lane & 15, quad = lane >> 4;
  const int mt = w & 1, nt = w >> 1;
  const int d = nt * 16 + l15;

  // prefetch ALL W fragments up front (latency hides under y staging)
  f16x8 wreg[8];
  {
    const f16x8* Wg8 = reinterpret_cast<const f16x8*>(Wy) + (size_t)jb * 2048;
    #pragma unroll
    for (int kt = 0; kt < 8; ++kt) wreg[kt] = Wg8[kt * 256 + d * 4 + quad];
  }
  f16x8 wt8r[8];
  if (!final_iter) {
    const f16x8* WT8 = reinterpret_cast<const f16x8*>(WTd) + (size_t)jb * 2048;
    #pragma unroll
    for (int qx = 0; qx < 4; ++qx) {
      const int cc = ((w >> 1) * 4 + qx) * 16 + l15;
      #pragma unroll
      for (int kt = 0; kt < 2; ++kt)
        wt8r[qx * 2 + kt] = WT8[kt * 1024 + cc * 4 + quad];
    }
  }

  #pragma unroll
  for (int p0 = 0; p0 < 2; ++p0) {
    const int p = p0 * 512 + t;
    const int bs = p >> 5, co = (p & 31) * 8;
    *reinterpret_cast<f16x8*>(&ysh[bs * 264 + co]) =
        *reinterpret_cast<const f16x8*>(
            &y16[(size_t)(b0 + bs) * 8192 + jb * 256 + co]);
  }
  if (t < 32) {
    csums[t] = csum_ws[(b0 + t) * 32 + jb];
    n2sh[t] = 0.f;
    vbsh[t] = 0.f;
  }
  __syncthreads();

  // ---- s-GEMM: wave w -> (mt, nt) ----
  f32x4 sacc = (f32x4){0.f, 0.f, 0.f, 0.f};
  #pragma unroll
  for (int kt = 0; kt < 8; ++kt) {
    const int ko = kt * 32 + quad * 8;
    f16x8 a = *reinterpret_cast<const f16x8*>(&ysh[(mt * 16 + l15) * 264 + ko]);
    sacc = __builtin_amdgcn_mfma_f32_16x16x32_f16(a, wreg[kt], sacc, 0, 0, 0);
  }
  const float biasd = bias[jb * 64 + d];
  float sv[4];
  #pragma unroll
  for (int rr = 0; rr < 4; ++rr)
    sv[rr] = sacc[rr] + biasd * csums[mt * 16 + quad * 4 + rr];

  #pragma unroll
  for (int rr = 0; rr < 4; ++rr) {
    float p = sv[rr] * sv[rr];
    p += __shfl_xor(p, 1);
    p += __shfl_xor(p, 2);
    p += __shfl_xor(p, 4);
    p += __shfl_xor(p, 8);
    if (l15 == 0) atomicAdd(&n2sh[mt * 16 + quad * 4 + rr], p);
  }
  __syncthreads();

  float vv[4];
  #pragma unroll
  for (int rr = 0; rr < 4; ++rr) {
    const float n2 = n2sh[mt * 16 + quad * 4 + rr];
    const float sc = sqrtf(n2) / (1.f + n2);
    vv[rr] = sv[rr] * sc;
  }

  if (final_iter) {
    #pragma unroll
    for (int rr = 0; rr < 4; ++rr)
      vout[((size_t)(b0 + mt * 16 + quad * 4 + rr) * 32 + jb) * 64 + d] = vv[rr];
  } else {
    #pragma unroll
    for (int rr = 0; rr < 4; ++rr) {
      vsh[(mt * 16 + quad * 4 + rr) * 72 + d] = (_Float16)vv[rr];
      float p = vv[rr] * biasd;
      p += __shfl_xor(p, 1);
      p += __shfl_xor(p, 2);
      p += __shfl_xor(p, 4);
      p += __shfl_xor(p, 8);
      if (l15 == 0) atomicAdd(&vbsh[mt * 16 + quad * 4 + rr], p);
    }
    __syncthreads();   // vsh/vbsh complete; ysh reads done -> reuse ysh
    if (t < 32) vb_ws[(b0 + t) * 32 + jb] = vbsh[t];

    // ---- u-GEMM: wave w -> (mt, ntu = (w>>1)*4 + qx), W in regs ----
    #pragma unroll
    for (int qx = 0; qx < 4; ++qx) {
      const int cc = ((w >> 1) * 4 + qx) * 16 + l15;
      f32x4 ua = (f32x4){0.f, 0.f, 0.f, 0.f};
      #pragma unroll
      for (int kt = 0; kt < 2; ++kt) {
        const int ko = kt * 32 + quad * 8;
        f16x8 a =
            *reinterpret_cast<const f16x8*>(&vsh[(mt * 16 + l15) * 72 + ko]);
        ua = __builtin_amdgcn_mfma_f32_16x16x32_f16(a, wt8r[qx * 2 + kt], ua, 0, 0, 0);
      }
      #pragma unroll
      for (int rr = 0; rr < 4; ++rr)
        ysh[(mt * 16 + quad * 4 + rr) * 264 + cc] = (_Float16)ua[rr];
    }
    __syncthreads();
    // coalesced u16 write-out
    #pragma unroll
    for (int p0 = 0; p0 < 2; ++p0) {
      const int p = p0 * 512 + t;
      const int bs = p >> 5, co = (p & 31) * 8;
      *reinterpret_cast<f16x8*>(&u16[(size_t)(b0 + bs) * 8192 + jb * 256 + co]) =
          *reinterpret_cast<const f16x8*>(&ysh[bs * 264 + co]);
    }
  }
}

// ---------------------------------------------------------------------------
extern "C" void kernel_launch(void* const* d_in, const int* in_sizes, int n_in,
                              void* d_out, int out_size, void* d_ws, size_t ws_size,
                              hipStream_t stream) {
  (void)in_sizes; (void)n_in; (void)out_size; (void)ws_size;
  const float* x      = (const float*)d_in[0];
  const float* W      = (const float*)d_in[1];
  const float* bias   = (const float*)d_in[2];
  const float* b_init = (const float*)d_in[3];
  char* ws = (char*)d_ws;

  _Float16* x16y = (_Float16*)(ws);                             // 32 MiB
  _Float16* y16  = (_Float16*)(ws + (32u << 20));               // 4 MiB
  _Float16* u16a = (_Float16*)(ws + (36u << 20));               // 4 MiB
  _Float16* u16b = (_Float16*)(ws + (40u << 20));               // 4 MiB
  float*    b2   = (float*)(ws + (44u << 20));                  // 8 MiB
  _Float16* Wy   = (_Float16*)(ws + (52u << 20));               // 1 MiB
  _Float16* WTd  = (_Float16*)(ws + (53u << 20));               // 1 MiB
  float*    csum = (float*)(ws + (54u << 20));                  // 32 KiB
  float*    vb0  = (float*)(ws + (54u << 20) + (32u << 10));    // 32 KiB
  float*    vb1  = (float*)(ws + (54u << 20) + (64u << 10));    // 32 KiB
  float*    vout = (float*)d_out;

  kXW<<<2080, 256, 0, stream>>>(x, W, x16y, Wy, WTd);
  // iter 1: softmax(b_init), y
  kR<<<256, 1024, 0, stream>>>(x16y, u16a, vb0, b_init, b2, y16, csum, 0);
  k2<<<256, 512, 0, stream>>>(Wy, WTd, bias, y16, csum, u16a, vb0, vout, 0);
  // iter 2: b = b_init + D(u0)+vb0, checkpoint b2
  kR<<<256, 1024, 0, stream>>>(x16y, u16a, vb0, b_init, b2, y16, csum, 1);
  k2<<<256, 512, 0, stream>>>(Wy, WTd, bias, y16, csum, u16b, vb1, vout, 0);
  // iter 3: b = b2 + D(u1)+vb1 (single delta pass)
  kR<<<256, 1024, 0, stream>>>(x16y, u16b, vb1, b2, b2, y16, csum, 2);
  k2<<<256, 512, 0, stream>>>(Wy, WTd, bias, y16, csum, u16a, vb0, vout, 1);
}